// Round 13
// baseline (599.239 us; speedup 1.0000x reference)
//
#include <hip/hip_runtime.h>
#include <hip/hip_bf16.h>
#include <math.h>

#define N_   32
#define C_   256
#define T_   128
#define V_   25
#define CTV  (C_ * T_ * V_)   // 819200
#define TV   (T_ * V_)        // 3200
#define EPS_ 1e-5f
#define S_Q  0.35355339059327373f
#define NCOPY 64

typedef __attribute__((ext_vector_type(8))) short bf16x8;
typedef __attribute__((ext_vector_type(4))) float f32x4;
typedef __attribute__((ext_vector_type(4))) unsigned short u16x4;

__device__ inline ushort f2b(float f) {
    __hip_bfloat16 h = __float2bfloat16(f);
    return *reinterpret_cast<ushort*>(&h);
}
__device__ inline float b2f(ushort u) {
    __hip_bfloat16 h;
    *reinterpret_cast<ushort*>(&h) = u;
    return __bfloat162float(h);
}
__device__ inline float tanh_fast(float x) {
    float xc = fminf(fmaxf(x, -12.f), 12.f);
    float e = __expf(xc + xc);
    return (e - 1.f) * __builtin_amdgcn_rcpf(e + 1.f);
}
#define LD8(p) (*(const bf16x8*)(p))
#define MFMA16(a, b, c) __builtin_amdgcn_mfma_f32_16x16x32_bf16(a, b, c, 0, 0, 0)

__device__ inline int qtswz(int v, int col) {   // LDS qkvT slice [32][320]
    return v * 320 + ((((col >> 3)) ^ (v & 7)) << 3) + (col & 7);
}
__device__ inline int qvswz(int e, int w) {     // (fallback) qkvV [256][32]
    return e * 32 + (((w >> 3) ^ (e & 3)) << 3) + (w & 7);
}
__device__ inline int bswz(int v, int c) {      // (fallback) B tile [32][256]
    return v * 256 + ((((c >> 3) ^ (v & 7)) << 3) | (c & 7));
}

// ---------------- shared prep kernels ----------------
__global__ void prep_kernel(const float* __restrict__ qkv_w,
                            const float* __restrict__ attn_w,
                            ushort* __restrict__ Wq, ushort* __restrict__ Wa,
                            float* __restrict__ pe, float* __restrict__ bins,
                            ushort* __restrict__ vout, int zero_vout) {
    int idx = blockIdx.x * blockDim.x + threadIdx.x;
    int stride = gridDim.x * blockDim.x;
    for (int i = idx; i < 448 * 256; i += stride) {
        float w = qkv_w[i];
        if (i < 64 * 256) w *= S_Q;
        Wq[i] = f2b(w);
    }
    for (int i = idx; i < 256 * 256; i += stride) Wa[i] = f2b(attn_w[i]);
    for (int i = idx; i < C_ * V_; i += stride) {
        int c = i / V_, v = i - c * V_;
        int j2 = c & ~1;
        float ang = (float)v * expf(-logf(10000.0f) * (float)j2 / (float)C_);
        pe[i] = (c & 1) ? cosf(ang) : sinf(ang);
    }
    for (int i = idx; i < NCOPY * 512; i += stride) bins[i] = 0.f;
    if (zero_vout) {   // zero pad lanes of vout [n][t][e][32]
        u16x4 z = {0, 0, 0, 0};
        u16x4* vp = (u16x4*)vout;
        for (int i = idx; i < 32 * 128 * 256 * 8; i += stride) vp[i] = z;
    }
}

__global__ __launch_bounds__(1024) void dbn_kernel(const float* __restrict__ x,
                                                   const float* __restrict__ gamma,
                                                   const float* __restrict__ beta,
                                                   float* __restrict__ a_scale,
                                                   float* __restrict__ a_shift) {
    __shared__ float pgS[32][25], pgQ[32][25];
    int c = blockIdx.x;
    int tid = threadIdx.x, g = tid >> 5, l = tid & 31;
    float s = 0.f, s2 = 0.f;
    if (l < 25) {
        const float* base = x + (size_t)g * CTV + c * TV + l;
        #pragma unroll 8
        for (int t = 0; t < 128; ++t) {
            float v = base[t * 25];
            s += v; s2 += v * v;
        }
        pgS[g][l] = s; pgQ[g][l] = s2;
    }
    __syncthreads();
    if (tid < 25) {
        float S = 0.f, Q = 0.f;
        #pragma unroll
        for (int g2 = 0; g2 < 32; ++g2) { S += pgS[g2][tid]; Q += pgQ[g2][tid]; }
        float inv = 1.0f / 4096.0f;
        float mean = S * inv, var = Q * inv - mean * mean;
        int f = c * 25 + tid;
        float sc = rsqrtf(var + EPS_) * gamma[f];
        a_scale[f] = sc;
        a_shift[f] = beta[f] - mean * sc;
    }
}

__global__ void mkbias_kernel(const ushort* __restrict__ Wq,
                              const float* __restrict__ qkv_b,
                              const float* __restrict__ a_shift,
                              const float* __restrict__ pe,
                              float* __restrict__ bias2, float* __restrict__ peproj) {
    int id = blockIdx.x * 256 + threadIdx.x;
    if (id < 11200) {
        int o = id / 25, v = id - o * 25;
        float acc = qkv_b[o] * (o < 64 ? S_Q : 1.f);
        for (int c = 0; c < 256; ++c)
            acc = fmaf(b2f(Wq[o * 256 + c]), a_shift[c * 25 + v], acc);
        bias2[id] = acc;
    } else if (id < 14400) {
        int id2 = id - 11200;
        int r = id2 / 25, v = id2 - r * 25;
        float acc = qkv_b[r] * (r < 64 ? S_Q : 1.f);
        for (int c = 0; c < 256; ++c)
            acc = fmaf(b2f(Wq[r * 256 + c]), pe[c * 25 + v], acc);
        peproj[id2] = acc;
    }
}

__global__ void b2sum_kernel(const float* __restrict__ bias2,
                             float* __restrict__ bias2sum) {
    int o = threadIdx.x;
    float s = 0.f;
    #pragma unroll
    for (int v = 0; v < 25; ++v) s += bias2[o * 25 + v];
    bias2sum[o] = s;
}

// ================= NEW PATH =================
// prepx: x [n][c][tv] f32 -> xnT [n][tv][c] (scaled), xrawT [n][tv][c] (raw), bf16
__global__ __launch_bounds__(256) void prepx_kernel(const float* __restrict__ x,
                                                    const float* __restrict__ a_scale,
                                                    ushort* __restrict__ xnT,
                                                    ushort* __restrict__ xrawT) {
    __shared__ float tile[64][65];
    int nt = blockIdx.x, ct = blockIdx.y, n = blockIdx.z;
    int tid = threadIdx.x;
    const float* xb = x + (size_t)n * CTV + ct * 64 * TV + nt * 64;
    #pragma unroll
    for (int it = 0; it < 16; ++it) {
        int idx = it * 256 + tid;
        int cc = idx >> 6, tv = idx & 63;
        tile[cc][tv] = xb[cc * TV + tv];
    }
    __syncthreads();
    #pragma unroll
    for (int it = 0; it < 16; ++it) {
        int idx = it * 256 + tid;
        int tv = idx >> 6, cc = idx & 63;
        int gtv = nt * 64 + tv, gc = ct * 64 + cc;
        float xv = tile[cc][tv];
        size_t off = ((size_t)n * 3200 + gtv) * 256 + gc;
        xrawT[off] = f2b(xv);
        xnT[off] = f2b(xv * a_scale[gc * 25 + gtv % 25]);
    }
}

// gemm1: rows 0..447 = Wq x xn, rows 448..575 = Wq[0:128] x xraw (+peproj)
// outputs: qkvT_g [n][tv][320] (q/k/g/pq/pk), vout [n][t][e][32]
__global__ __launch_bounds__(256) void gemm1_kernel(
        const ushort* __restrict__ xnT, const ushort* __restrict__ xrawT,
        const ushort* __restrict__ Wq,
        const float* __restrict__ bias2, const float* __restrict__ peproj,
        ushort* __restrict__ qkvT_g, ushort* __restrict__ vout) {
    int nt = blockIdx.x, mt = blockIdx.y, n = blockIdx.z;
    int tid = threadIdx.x, wave = tid >> 6, lane = tid & 63;
    int lr = lane & 15, lg = lane >> 4;
    const f32x4 zacc = {0.f, 0.f, 0.f, 0.f};
    bool pos = (mt >= 7);
    int rbase = mt * 64 + wave * 16;
    int wrow = pos ? rbase - 448 : rbase;
    const ushort* Arow = Wq + (wrow + lr) * 256;
    const ushort* Bbase = (pos ? xrawT : xnT) + ((size_t)n * 3200 + nt * 64) * 256;
    f32x4 acc[4];
    acc[0] = zacc; acc[1] = zacc; acc[2] = zacc; acc[3] = zacc;
    #pragma unroll
    for (int kk = 0; kk < 8; ++kk) {
        int k0 = kk * 32 + lg * 8;
        bf16x8 a = LD8(Arow + k0);
        #pragma unroll
        for (int ni = 0; ni < 4; ++ni) {
            bf16x8 b = LD8(Bbase + (ni * 16 + lr) * 256 + k0);
            acc[ni] = MFMA16(a, b, acc[ni]);
        }
    }
    #pragma unroll
    for (int ni = 0; ni < 4; ++ni) {
        int col = nt * 64 + ni * 16 + lr;
        int v = col % 25;
        int rb = rbase + lg * 4;
        if (mt <= 2 || pos) {
            int qcol = pos ? rb - 256 : rb;   // pq/pk -> cols 192..319
            u16x4 r4;
            #pragma unroll
            for (int i2 = 0; i2 < 4; ++i2) {
                float bsv = pos ? peproj[(rb - 448 + i2) * 25 + v]
                                : bias2[(rb + i2) * 25 + v];
                r4[i2] = f2b(acc[ni][i2] + bsv);
            }
            *(u16x4*)(qkvT_g + ((size_t)n * 3200 + col) * 320 + qcol) = r4;
        } else {
            int t = col / 25;
            #pragma unroll
            for (int i2 = 0; i2 < 4; ++i2) {
                int e = rb - 192 + i2;
                vout[(((size_t)n * 128 + t) * 256 + e) * 32 + v] =
                    f2b(acc[ni][i2] + bias2[(rb + i2) * 25 + v]);
            }
        }
    }
}

// attnmid: per token, weights = tanh(P1) + tanh(P2); attn = weights x V -> attnT [n][tv][256]
__global__ __launch_bounds__(512) void attnmid_kernel(
        const ushort* __restrict__ qkvT_g, const ushort* __restrict__ vout,
        ushort* __restrict__ attnT_g) {
    __shared__ __align__(16) char smem[20736];
    ushort* qslice = (ushort*)smem;            // [32][320] swz; later pbuf [8][32][40]
    ushort* pbuf = (ushort*)smem;
    ushort* qmub = (ushort*)(smem + 20480);    // bf16[128]: mu | -mu
    int blk = blockIdx.x;
    int n = blk >> 7, t = blk & 127;
    int tid = threadIdx.x, wave = tid >> 6, lane = tid & 63;
    int lr = lane & 15, lg = lane >> 4;
    const f32x4 zacc = {0.f, 0.f, 0.f, 0.f};
    const bf16x8 zero8 = {0, 0, 0, 0, 0, 0, 0, 0};
    size_t tvbase = (size_t)n * 3200 + t * 25;

    for (int i = tid; i < 2000; i += 512) {
        int v = i / 80, c4 = (i - v * 80) * 4;
        *(u16x4*)(qslice + qtswz(v, c4)) =
            *(const u16x4*)(qkvT_g + (tvbase + v) * 320 + c4);
    }
    for (int i = tid; i < 560; i += 512) {
        int v = 25 + i / 80, c4 = (i % 80) * 4;
        u16x4 z = {0, 0, 0, 0};
        *(u16x4*)(qslice + qtswz(v, c4)) = z;
    }
    __syncthreads();   // B1

    int h = wave;
    if (lane < 8) {
        int o = h * 8 + lane;
        float s = 0.f;
        #pragma unroll
        for (int v = 0; v < 25; ++v)
            s += b2f(qslice[v * 320 + (((o >> 3) ^ (v & 7)) << 3) + (o & 7)]);
        s *= (1.f / 25.f);
        qmub[o] = f2b(s);
        qmub[64 + o] = f2b(-s);
    }
    __syncthreads();   // B1b (mu visible)

    bf16x8 mu8 = LD8(qmub + h * 8);
    bf16x8 mun8 = LD8(qmub + 64 + h * 8);
    bf16x8 aP1[2], aP2[2], bP1[2], bP2[2];
    #pragma unroll
    for (int mi = 0; mi < 2; ++mi) {
        int row = mi * 16 + lr, sx = row & 7;
        const ushort* rp = qslice + row * 320;
        aP1[mi] = (lg == 0) ? LD8(rp + ((h ^ sx) << 3))
                : (lg == 1) ? LD8(rp + (((24 + h) ^ sx) << 3))
                : (lg == 2) ? mun8 : zero8;
        bP1[mi] = (lg == 0) ? LD8(rp + (((8 + h) ^ sx) << 3))
                : (lg == 1) ? LD8(rp + (((32 + h) ^ sx) << 3))
                : (lg == 2) ? LD8(rp + (((8 + h) ^ sx) << 3)) : zero8;
        aP2[mi] = (lg == 0) ? LD8(rp + (((24 + h) ^ sx) << 3))
                : (lg == 1) ? mu8 : zero8;
        bP2[mi] = (lg == 0) ? LD8(rp + (((32 + h) ^ sx) << 3))
                : (lg == 1) ? LD8(rp + (((16 + h) ^ sx) << 3)) : zero8;
    }
    f32x4 p1[2][2], p2[2][2];
    #pragma unroll
    for (int mi = 0; mi < 2; ++mi)
        #pragma unroll
        for (int ni = 0; ni < 2; ++ni) {
            p1[mi][ni] = MFMA16(aP1[mi], bP1[ni], zacc);
            p2[mi][ni] = MFMA16(aP2[mi], bP2[ni], zacc);
        }
    __syncthreads();   // B2: qslice reads done -> pbuf may overwrite

    #pragma unroll
    for (int mi = 0; mi < 2; ++mi)
        #pragma unroll
        for (int ni = 0; ni < 2; ++ni) {
            int w = ni * 16 + lr;
            #pragma unroll
            for (int i2 = 0; i2 < 4; ++i2) {
                int v = mi * 16 + lg * 4 + i2;
                float tw = tanh_fast(p1[mi][ni][i2]) + tanh_fast(p2[mi][ni][i2]);
                pbuf[(h * 32 + v) * 40 + w] = (w < 25) ? f2b(tw) : (ushort)0;
            }
        }

    f32x4 at_[2][2];
    {
        bf16x8 aw[2], bv[2];
        #pragma unroll
        for (int mi = 0; mi < 2; ++mi)
            aw[mi] = LD8(pbuf + (h * 32 + mi * 16 + lr) * 40 + lg * 8);
        #pragma unroll
        for (int ni = 0; ni < 2; ++ni) {
            int e = h * 32 + ni * 16 + lr;
            bv[ni] = LD8(vout + (((size_t)n * 128 + t) * 256 + e) * 32 + lg * 8);
        }
        #pragma unroll
        for (int mi = 0; mi < 2; ++mi)
            #pragma unroll
            for (int ni = 0; ni < 2; ++ni)
                at_[mi][ni] = MFMA16(aw[mi], bv[ni], zacc);
    }
    #pragma unroll
    for (int mi = 0; mi < 2; ++mi)
        #pragma unroll
        for (int ni = 0; ni < 2; ++ni)
            #pragma unroll
            for (int i2 = 0; i2 < 4; ++i2) {
                int v = mi * 16 + lg * 4 + i2;
                int e = h * 32 + ni * 16 + lr;
                if (v < 25) attnT_g[(tvbase + v) * 256 + e] = f2b(at_[mi][ni][i2]);
            }
}

// gemm2: out = Wa x attn + bias + skip; fused bn2 partials
__global__ __launch_bounds__(256) void gemm2_kernel(
        const ushort* __restrict__ Wa, const ushort* __restrict__ attnT_g,
        const float* __restrict__ attn_b, const float* __restrict__ x,
        float* __restrict__ out, float* __restrict__ bins) {
    int nt = blockIdx.x, mt = blockIdx.y, n = blockIdx.z;
    int tid = threadIdx.x, wave = tid >> 6, lane = tid & 63;
    int lr = lane & 15, lg = lane >> 4;
    const f32x4 zacc = {0.f, 0.f, 0.f, 0.f};
    int o_base = mt * 64 + wave * 16;
    const ushort* Arow = Wa + (o_base + lr) * 256;
    const ushort* Bbase = attnT_g + ((size_t)n * 3200 + nt * 64) * 256;
    f32x4 acc[4];
    acc[0] = zacc; acc[1] = zacc; acc[2] = zacc; acc[3] = zacc;
    #pragma unroll
    for (int kk = 0; kk < 8; ++kk) {
        int k0 = kk * 32 + lg * 8;
        bf16x8 a = LD8(Arow + k0);
        #pragma unroll
        for (int ni = 0; ni < 4; ++ni) {
            bf16x8 b = LD8(Bbase + (ni * 16 + lr) * 256 + k0);
            acc[ni] = MFMA16(a, b, acc[ni]);
        }
    }
    float* mybins = bins + ((nt + mt * 50 + n * 200) & (NCOPY - 1)) * 512;
    #pragma unroll
    for (int i2 = 0; i2 < 4; ++i2) {
        int o = o_base + lg * 4 + i2;
        float bias = attn_b[o];
        float cs = 0.f, cq = 0.f;
        #pragma unroll
        for (int ni = 0; ni < 4; ++ni) {
            int col = nt * 64 + ni * 16 + lr;
            size_t off = ((size_t)n * 256 + o) * 3200 + col;
            float v0 = acc[ni][i2] + bias + x[off];
            out[off] = v0;
            cs += v0; cq += v0 * v0;
        }
        #pragma unroll
        for (int mm = 1; mm < 16; mm <<= 1) {
            cs += __shfl_xor(cs, mm, 64);
            cq += __shfl_xor(cq, mm, 64);
        }
        if (lr == 0) {
            atomicAdd(&mybins[o], cs);
            atomicAdd(&mybins[256 + o], cq);
        }
    }
}

// ================= FALLBACK (round-9 fused kernel) =================
__global__ __launch_bounds__(512, 4) void fused_kernel_fb(
        const float* __restrict__ x,
        const ushort* __restrict__ Wq,
        const float* __restrict__ bias2, const float* __restrict__ peproj,
        const float* __restrict__ a_scale, const float* __restrict__ bias2sum,
        const ushort* __restrict__ Wa, const float* __restrict__ attn_b,
        float* __restrict__ out, float* __restrict__ bins) {
    __shared__ __align__(16) char smem[53376];
    ushort* Braw = (ushort*)smem;
    ushort* Bxn  = (ushort*)(smem + 16384);
    ushort* qkvT = (ushort*)(smem + 32768);
    ushort* qkvV = (ushort*)smem;
    ushort* aT   = (ushort*)(smem + 16384);
    ushort* pbuf = (ushort*)(smem + 32768);
    ushort* qmub = (ushort*)(smem + 53248);

    int n = blockIdx.x >> 7, t = blockIdx.x & 127;
    int tid = threadIdx.x, wave = tid >> 6, lane = tid & 63;
    int lr = lane & 15, lg = lane >> 4;
    const float* xp = x + (size_t)n * CTV + t * V_;
    float* outp = out + (size_t)n * CTV + t * V_;
    float* mybins = bins + (blockIdx.x & (NCOPY - 1)) * 512;
    const f32x4 zacc = {0.f, 0.f, 0.f, 0.f};
    const bf16x8 zero8 = {0, 0, 0, 0, 0, 0, 0, 0};

    float b2s[4] = {0.f, 0.f, 0.f, 0.f};
    if (wave < 4) {
        #pragma unroll
        for (int i2 = 0; i2 < 4; ++i2)
            b2s[i2] = bias2sum[wave * 16 + lg * 4 + i2];
    }
    {
        float xv[13], sc[13];
        #pragma unroll
        for (int j = 0; j < 13; ++j) {
            int i = tid + j * 512;
            if (i < 6400) {
                int c = i / 25, v = i - c * 25;
                xv[j] = xp[c * TV + v];
                sc[j] = a_scale[i];
            }
        }
        #pragma unroll
        for (int j = 0; j < 13; ++j) {
            int i = tid + j * 512;
            if (i < 6400) {
                int c = i / 25, v = i - c * 25;
                int off = bswz(v, c);
                Braw[off] = f2b(xv[j]);
                Bxn[off]  = f2b(xv[j] * sc[j]);
            }
        }
        for (int i = tid; i < 448; i += 512) {
            int v = 25 + (i >> 6), cz = (i & 63) * 4;
            u16x4 z4 = {0, 0, 0, 0};
            *(u16x4*)(Braw + v * 256 + cz) = z4;
            *(u16x4*)(Bxn + v * 256 + cz) = z4;
        }
    }
    __syncthreads();
    {
        const ushort* Arow = Wq + (wave * 16 + lr) * 256;
        f32x4 a0 = zacc, a1 = zacc;
        #pragma unroll
        for (int kk = 0; kk < 8; ++kk) {
            int k0 = kk * 32 + lg * 8;
            int oct = (((k0 >> 3) ^ (lr & 7)) << 3);
            bf16x8 a  = LD8(Arow + k0);
            bf16x8 b0 = LD8(Braw + lr * 256 + oct);
            bf16x8 b1 = LD8(Braw + (16 + lr) * 256 + oct);
            a0 = MFMA16(a, b0, a0);
            a1 = MFMA16(a, b1, a1);
        }
        int rb = wave * 16 + lg * 4;
        u16x4 r0, r1;
        #pragma unroll
        for (int i2 = 0; i2 < 4; ++i2) {
            int r = rb + i2;
            r0[i2] = f2b(a0[i2] + peproj[r * 25 + lr]);
            r1[i2] = (lr < 9) ? f2b(a1[i2] + peproj[r * 25 + 16 + lr]) : (ushort)0;
        }
        *(u16x4*)(qkvT + qtswz(lr, 192 + rb)) = r0;
        *(u16x4*)(qkvT + qtswz(16 + lr, 192 + rb)) = r1;
    }
    __syncthreads();
    {
        int myTiles = (wave < 4) ? 4 : 3;
        f32x4 acc[4][2];
        #pragma unroll
        for (int i = 0; i < 4; ++i) { acc[i][0] = zacc; acc[i][1] = zacc; }
        #pragma unroll
        for (int kk = 0; kk < 8; ++kk) {
            int k0 = kk * 32 + lg * 8;
            int oct = (((k0 >> 3) ^ (lr & 7)) << 3);
            bf16x8 b0 = LD8(Bxn + lr * 256 + oct);
            bf16x8 b1 = LD8(Bxn + (16 + lr) * 256 + oct);
            #pragma unroll
            for (int tt = 0; tt < 4; ++tt) {
                if (tt < myTiles) {
                    int mt = wave + tt * 8;
                    bf16x8 a = LD8(Wq + (mt * 16 + lr) * 256 + k0);
                    acc[tt][0] = MFMA16(a, b0, acc[tt][0]);
                    acc[tt][1] = MFMA16(a, b1, acc[tt][1]);
                }
            }
        }
        #pragma unroll
        for (int tt = 0; tt < 4; ++tt) {
            if (tt < myTiles) {
                int mt = wave + tt * 8;
                int ob = mt * 16 + lg * 4;
                if (mt < 4) {
                    u16x4 r0, r1;
                    #pragma unroll
                    for (int i2 = 0; i2 < 4; ++i2) {
                        int o = ob + i2;
                        float cs = acc[tt][0][i2] + ((lr < 9) ? acc[tt][1][i2] : 0.f);
                        #pragma unroll
                        for (int mm = 1; mm < 16; mm <<= 1)
                            cs += __shfl_xor(cs, mm, 64);
                        float mu = (cs + b2s[i2]) * 0.04f;
                        ushort mur = f2b(mu);
                        float muf = b2f(mur);
                        r0[i2] = f2b(acc[tt][0][i2] + bias2[o * 25 + lr] - muf);
                        r1[i2] = (lr < 9)
                            ? f2b(acc[tt][1][i2] + bias2[o * 25 + 16 + lr] - muf)
                            : (ushort)0;
                        if (lr == 0) qmub[o] = mur;
                    }
                    *(u16x4*)(qkvT + qtswz(lr, ob)) = r0;
                    *(u16x4*)(qkvT + qtswz(16 + lr, ob)) = r1;
                } else if (mt < 12) {
                    u16x4 r0, r1;
                    #pragma unroll
                    for (int i2 = 0; i2 < 4; ++i2) {
                        int o = ob + i2;
                        r0[i2] = f2b(acc[tt][0][i2] + bias2[o * 25 + lr]);
                        r1[i2] = (lr < 9)
                            ? f2b(acc[tt][1][i2] + bias2[o * 25 + 16 + lr])
                            : (ushort)0;
                    }
                    *(u16x4*)(qkvT + qtswz(lr, ob)) = r0;
                    *(u16x4*)(qkvT + qtswz(16 + lr, ob)) = r1;
                } else {
                    #pragma unroll
                    for (int i2 = 0; i2 < 4; ++i2) {
                        int o = ob + i2;
                        int e = o - 192;
                        qkvV[qvswz(e, lr)] = f2b(acc[tt][0][i2] + bias2[o * 25 + lr]);
                        qkvV[qvswz(e, 16 + lr)] = (lr < 9)
                            ? f2b(acc[tt][1][i2] + bias2[o * 25 + 16 + lr])
                            : (ushort)0;
                    }
                }
            }
        }
    }
    __syncthreads();
    int h = wave;
    bf16x8 mu8 = LD8(qmub + h * 8);
    bf16x8 aP1[2], aP2[2], bP1[2], bP2[2];
    #pragma unroll
    for (int mi = 0; mi < 2; ++mi) {
        int row = mi * 16 + lr, sx = row & 7;
        const ushort* rp = qkvT + row * 320;
        aP1[mi] = (lg == 0) ? LD8(rp + ((h ^ sx) << 3))
                : (lg == 1) ? LD8(rp + (((24 + h) ^ sx) << 3)) : zero8;
        aP2[mi] = (lg == 0) ? LD8(rp + (((24 + h) ^ sx) << 3))
                : (lg == 1) ? mu8 : zero8;
        bP1[mi] = (lg == 0) ? LD8(rp + (((8 + h) ^ sx) << 3))
                : (lg == 1) ? LD8(rp + (((32 + h) ^ sx) << 3)) : zero8;
        bP2[mi] = (lg == 0) ? LD8(rp + (((32 + h) ^ sx) << 3))
                : (lg == 1) ? LD8(rp + (((16 + h) ^ sx) << 3)) : zero8;
    }
    f32x4 p1[2][2], p2[2][2];
    #pragma unroll
    for (int mi = 0; mi < 2; ++mi)
        #pragma unroll
        for (int ni = 0; ni < 2; ++ni) {
            p1[mi][ni] = MFMA16(aP1[mi], bP1[ni], zacc);
            p2[mi][ni] = MFMA16(aP2[mi], bP2[ni], zacc);
        }
    __syncthreads();
    #pragma unroll
    for (int mi = 0; mi < 2; ++mi)
        #pragma unroll
        for (int ni = 0; ni < 2; ++ni) {
            int w = ni * 16 + lr;
            #pragma unroll
            for (int i2 = 0; i2 < 4; ++i2) {
                int v = mi * 16 + lg * 4 + i2;
                float tw = tanh_fast(p1[mi][ni][i2]) + tanh_fast(p2[mi][ni][i2]);
                pbuf[(h * 32 + v) * 40 + w] = (w < 25) ? f2b(tw) : (ushort)0;
            }
        }
    {
        bf16x8 aw[2], bv[2];
        #pragma unroll
        for (int mi = 0; mi < 2; ++mi)
            aw[mi] = LD8(pbuf + (h * 32 + mi * 16 + lr) * 40 + lg * 8);
        #pragma unroll
        for (int ni = 0; ni < 2; ++ni) {
            int e = h * 32 + ni * 16 + lr;
            bv[ni] = LD8(qkvV + e * 32 + ((lg ^ (e & 3)) << 3));
        }
        f32x4 at_[2][2];
        #pragma unroll
        for (int mi = 0; mi < 2; ++mi)
            #pragma unroll
            for (int ni = 0; ni < 2; ++ni)
                at_[mi][ni] = MFMA16(aw[mi], bv[ni], zacc);
        #pragma unroll
        for (int mi = 0; mi < 2; ++mi)
            #pragma unroll
            for (int ni = 0; ni < 2; ++ni)
                #pragma unroll
                for (int i2 = 0; i2 < 4; ++i2) {
                    int v = mi * 16 + lg * 4 + i2;
                    int e = h * 32 + ni * 16 + lr;
                    if (v < 25) aT[bswz(v, e)] = f2b(at_[mi][ni][i2]);
                }
    }
    __syncthreads();
    float sk0[2][4], sk1[2][4];
    #pragma unroll
    for (int tt = 0; tt < 2; ++tt)
        #pragma unroll
        for (int i2 = 0; i2 < 4; ++i2) {
            int o = (wave + tt * 8) * 16 + lg * 4 + i2;
            sk0[tt][i2] = xp[o * TV + lr];
            sk1[tt][i2] = (lr < 9) ? xp[o * TV + 16 + lr] : 0.f;
        }
    #pragma unroll
    for (int tt = 0; tt < 2; ++tt) {
        int o0 = (wave + tt * 8) * 16;
        const ushort* Arow = Wa + (o0 + lr) * 256;
        f32x4 a0 = zacc, a1 = zacc;
        #pragma unroll
        for (int kk = 0; kk < 8; ++kk) {
            int k0 = kk * 32 + lg * 8;
            int oct = (((k0 >> 3) ^ (lr & 7)) << 3);
            bf16x8 a  = LD8(Arow + k0);
            bf16x8 b0 = LD8(aT + lr * 256 + oct);
            bf16x8 b1 = LD8(aT + (16 + lr) * 256 + oct);
            a0 = MFMA16(a, b0, a0);
            a1 = MFMA16(a, b1, a1);
        }
        #pragma unroll
        for (int i2 = 0; i2 < 4; ++i2) {
            int o = o0 + lg * 4 + i2;
            float bias = attn_b[o];
            float v0 = a0[i2] + bias + sk0[tt][i2];
            outp[o * TV + lr] = v0;
            float v1 = 0.f;
            if (lr < 9) {
                v1 = a1[i2] + bias + sk1[tt][i2];
                outp[o * TV + 16 + lr] = v1;
            }
            float cs = v0 + v1, cq = v0 * v0 + v1 * v1;
            #pragma unroll
            for (int mm = 1; mm < 16; mm <<= 1) {
                cs += __shfl_xor(cs, mm, 64);
                cq += __shfl_xor(cq, mm, 64);
            }
            if (lr == 0) {
                atomicAdd(&mybins[o], cs);
                atomicAdd(&mybins[256 + o], cq);
            }
        }
    }
}

// ---------------- bn2 final + apply ----------------
__global__ void bn2_final_kernel(const float* __restrict__ bins,
                                 const float* __restrict__ gamma,
                                 const float* __restrict__ beta,
                                 float* __restrict__ scale,
                                 float* __restrict__ shift) {
    int c = threadIdx.x;
    float s = 0.f, q = 0.f;
    for (int cp = 0; cp < NCOPY; ++cp) {
        s += bins[cp * 512 + c];
        q += bins[cp * 512 + 256 + c];
    }
    float inv = 1.0f / (float)(N_ * TV);
    float mean = s * inv;
    float var = q * inv - mean * mean;
    float sc = rsqrtf(var + EPS_) * gamma[c];
    scale[c] = sc;
    shift[c] = beta[c] - mean * sc;
}

__global__ void bn2_apply_kernel(float4* __restrict__ y,
                                 const float* __restrict__ scale,
                                 const float* __restrict__ shift) {
    const int total4 = N_ * CTV / 4;
    for (int i = blockIdx.x * blockDim.x + threadIdx.x; i < total4;
         i += gridDim.x * blockDim.x) {
        int c = (i / (TV / 4)) & 255;
        float4 v = y[i];
        float sc = scale[c], sh = shift[c];
        v.x = fmaxf(fmaf(v.x, sc, sh), 0.f);
        v.y = fmaxf(fmaf(v.y, sc, sh), 0.f);
        v.z = fmaxf(fmaf(v.z, sc, sh), 0.f);
        v.w = fmaxf(fmaf(v.w, sc, sh), 0.f);
        y[i] = v;
    }
}

extern "C" void kernel_launch(void* const* d_in, const int* in_sizes, int n_in,
                              void* d_out, int out_size, void* d_ws, size_t ws_size,
                              hipStream_t stream) {
    const float* x      = (const float*)d_in[0];
    const float* qkv_w  = (const float*)d_in[1];
    const float* qkv_b  = (const float*)d_in[2];
    const float* attn_w = (const float*)d_in[3];
    const float* attn_b = (const float*)d_in[4];
    const float* dbn_g  = (const float*)d_in[5];
    const float* dbn_b  = (const float*)d_in[6];
    const float* bn_g   = (const float*)d_in[7];
    const float* bn_b   = (const float*)d_in[8];
    float* out = (float*)d_out;

    char* ws = (char*)d_ws;
    ushort* Wq       = (ushort*)ws;                 // 229376 B
    ushort* Wa       = (ushort*)(ws + 229376);      // 131072 B
    float*  pe       = (float*)(ws + 360448);       // 25600 B
    float*  a_scale  = (float*)(ws + 386048);       // 25600 B
    float*  a_shift  = (float*)(ws + 411648);       // 25600 B
    float*  bias2    = (float*)(ws + 437248);       // 44800 B
    float*  peproj   = (float*)(ws + 482048);       // 12800 B
    float*  bias2sum = (float*)(ws + 494848);       // 256 B
    float*  bins     = (float*)(ws + 495104);       // 131072 B
    float*  bn2_sc   = (float*)(ws + 626176);       // 1024 B
    float*  bn2_sh   = (float*)(ws + 627200);       // 1024 B
    ushort* qkvT_g   = (ushort*)(ws + 628224);      // 65,536,000 B
    ushort* voutg    = (ushort*)(ws + 66164224);    // 67,108,864 B
    ushort* attnT_g  = (ushort*)(ws + 133273088);   // 52,428,800 B
    const size_t NEEDED = 185701888;

    bool big = (ws_size >= NEEDED);

    prep_kernel<<<256, 256, 0, stream>>>(qkv_w, attn_w, Wq, Wa, pe, bins,
                                         voutg, big ? 1 : 0);
    dbn_kernel<<<C_, 1024, 0, stream>>>(x, dbn_g, dbn_b, a_scale, a_shift);
    mkbias_kernel<<<57, 256, 0, stream>>>(Wq, qkv_b, a_shift, pe, bias2, peproj);

    if (big) {
        // d_out doubles as scratch for xnT/xrawT until gemm2 writes it
        ushort* xnT = (ushort*)d_out;
        ushort* xrawT = xnT + 26214400;
        prepx_kernel<<<dim3(50, 4, 32), 256, 0, stream>>>(x, a_scale, xnT, xrawT);
        gemm1_kernel<<<dim3(50, 9, 32), 256, 0, stream>>>(xnT, xrawT, Wq, bias2,
                                                          peproj, qkvT_g, voutg);
        attnmid_kernel<<<N_ * T_, 512, 0, stream>>>(qkvT_g, voutg, attnT_g);
        gemm2_kernel<<<dim3(50, 4, 32), 256, 0, stream>>>(Wa, attnT_g, attn_b,
                                                          x, out, bins);
    } else {
        b2sum_kernel<<<1, 64, 0, stream>>>(bias2, bias2sum);
        fused_kernel_fb<<<N_ * T_, 512, 0, stream>>>(x, Wq, bias2, peproj, a_scale,
                                                     bias2sum, Wa, attn_b, out, bins);
    }
    bn2_final_kernel<<<1, 256, 0, stream>>>(bins, bn_g, bn_b, bn2_sc, bn2_sh);
    bn2_apply_kernel<<<4096, 256, 0, stream>>>((float4*)out, bn2_sc, bn2_sh);
}

// Round 14
// 383.470 us; speedup vs baseline: 1.5627x; 1.5627x over previous
//
#include <hip/hip_runtime.h>
#include <hip/hip_bf16.h>
#include <math.h>

#define N_   32
#define C_   256
#define T_   128
#define V_   25
#define CTV  (C_ * T_ * V_)   // 819200
#define TV   (T_ * V_)        // 3200
#define EPS_ 1e-5f
#define S_Q  0.35355339059327373f
#define NCOPY 64

typedef __attribute__((ext_vector_type(8))) short bf16x8;
typedef __attribute__((ext_vector_type(4))) float f32x4;
typedef __attribute__((ext_vector_type(4))) unsigned short u16x4;

__device__ inline ushort f2b(float f) {
    __hip_bfloat16 h = __float2bfloat16(f);
    return *reinterpret_cast<ushort*>(&h);
}
__device__ inline float b2f(ushort u) {
    __hip_bfloat16 h;
    *reinterpret_cast<ushort*>(&h) = u;
    return __bfloat162float(h);
}
__device__ inline float tanh_fast(float x) {
    float xc = fminf(fmaxf(x, -12.f), 12.f);
    float e = __expf(xc + xc);
    return (e - 1.f) * __builtin_amdgcn_rcpf(e + 1.f);
}
#define LD8(p) (*(const bf16x8*)(p))
#define MFMA16(a, b, c) __builtin_amdgcn_mfma_f32_16x16x32_bf16(a, b, c, 0, 0, 0)

// qkvT (swizzled, [32 v][320]): cols 0..63 q(centered) | 64..127 k | 128..191 g | 192..255 pq | 256..319 pk
__device__ inline int qtswz(int v, int col) {
    return v * 320 + ((((col >> 3)) ^ (v & 7)) << 3) + (col & 7);
}
__device__ inline int qvswz(int e, int w) {     // qkvV [256][32]
    return e * 32 + (((w >> 3) ^ (e & 3)) << 3) + (w & 7);
}
__device__ inline int bswz(int v, int c) {      // B tiles / aT [32][256]
    return v * 256 + ((((c >> 3) ^ (v & 7)) << 3) | (c & 7));
}

// ---------------- prep ----------------
__global__ void prep_kernel(const float* __restrict__ qkv_w,
                            const float* __restrict__ attn_w,
                            ushort* __restrict__ Wq, ushort* __restrict__ Wa,
                            float* __restrict__ pe, float* __restrict__ bins) {
    int idx = blockIdx.x * blockDim.x + threadIdx.x;
    int stride = gridDim.x * blockDim.x;
    for (int i = idx; i < 448 * 256; i += stride) {
        float w = qkv_w[i];
        if (i < 64 * 256) w *= S_Q;
        Wq[i] = f2b(w);
    }
    for (int i = idx; i < 256 * 256; i += stride) Wa[i] = f2b(attn_w[i]);
    for (int i = idx; i < C_ * V_; i += stride) {
        int c = i / V_, v = i - c * V_;
        int j2 = c & ~1;
        float ang = (float)v * expf(-logf(10000.0f) * (float)j2 / (float)C_);
        pe[i] = (c & 1) ? cosf(ang) : sinf(ang);
    }
    for (int i = idx; i < NCOPY * 512; i += stride) bins[i] = 0.f;
}

// ---------------- data_bn stats ----------------
__global__ __launch_bounds__(1024) void dbn_kernel(const float* __restrict__ x,
                                                   const float* __restrict__ gamma,
                                                   const float* __restrict__ beta,
                                                   float* __restrict__ a_scale,
                                                   float* __restrict__ a_shift) {
    __shared__ float pgS[32][25], pgQ[32][25];
    int c = blockIdx.x;
    int tid = threadIdx.x, g = tid >> 5, l = tid & 31;
    float s = 0.f, s2 = 0.f;
    if (l < 25) {
        const float* base = x + (size_t)g * CTV + c * TV + l;
        #pragma unroll 8
        for (int t = 0; t < 128; ++t) {
            float v = base[t * 25];
            s += v; s2 += v * v;
        }
        pgS[g][l] = s; pgQ[g][l] = s2;
    }
    __syncthreads();
    if (tid < 25) {
        float S = 0.f, Q = 0.f;
        #pragma unroll
        for (int g2 = 0; g2 < 32; ++g2) { S += pgS[g2][tid]; Q += pgQ[g2][tid]; }
        float inv = 1.0f / 4096.0f;
        float mean = S * inv, var = Q * inv - mean * mean;
        int f = c * 25 + tid;
        float sc = rsqrtf(var + EPS_) * gamma[f];
        a_scale[f] = sc;
        a_shift[f] = beta[f] - mean * sc;
    }
}

// ---------------- bias2 / peproj ----------------
__global__ void mkbias_kernel(const ushort* __restrict__ Wq,
                              const float* __restrict__ qkv_b,
                              const float* __restrict__ a_shift,
                              const float* __restrict__ pe,
                              float* __restrict__ bias2, float* __restrict__ peproj) {
    int id = blockIdx.x * 256 + threadIdx.x;
    if (id < 11200) {
        int o = id / 25, v = id - o * 25;
        float acc = qkv_b[o] * (o < 64 ? S_Q : 1.f);
        for (int c = 0; c < 256; ++c)
            acc = fmaf(b2f(Wq[o * 256 + c]), a_shift[c * 25 + v], acc);
        bias2[id] = acc;
    } else if (id < 14400) {
        int id2 = id - 11200;
        int r = id2 / 25, v = id2 - r * 25;
        float acc = qkv_b[r] * (r < 64 ? S_Q : 1.f);
        for (int c = 0; c < 256; ++c)
            acc = fmaf(b2f(Wq[r * 256 + c]), pe[c * 25 + v], acc);
        peproj[id2] = acc;
    }
}

__global__ void b2sum_kernel(const float* __restrict__ bias2,
                             float* __restrict__ bias2sum) {
    int o = threadIdx.x;   // 64
    float s = 0.f;
    #pragma unroll
    for (int v = 0; v < 25; ++v) s += bias2[o * 25 + v];
    bias2sum[o] = s;
}

// ---------------- fused per-token kernel (round-9 base + merged GEMM1) ----------------
__global__ __launch_bounds__(512, 4) void fused_kernel(
        const float* __restrict__ x,
        const ushort* __restrict__ Wq,
        const float* __restrict__ bias2, const float* __restrict__ peproj,
        const float* __restrict__ a_scale, const float* __restrict__ bias2sum,
        const ushort* __restrict__ Wa, const float* __restrict__ attn_b,
        float* __restrict__ out, float* __restrict__ bins) {
    // X [0,16384) Braw -> qkvV ; Y [16384,32768) Bxn -> aT ;
    // Z [32768,53248) qkvT -> pbuf ; [53248,53376) qmub (bf16[64])
    __shared__ __align__(16) char smem[53376];
    ushort* Braw = (ushort*)smem;
    ushort* Bxn  = (ushort*)(smem + 16384);
    ushort* qkvT = (ushort*)(smem + 32768);
    ushort* qkvV = (ushort*)smem;
    ushort* aT   = (ushort*)(smem + 16384);
    ushort* pbuf = (ushort*)(smem + 32768);
    ushort* qmub = (ushort*)(smem + 53248);

    int n = blockIdx.x >> 7, t = blockIdx.x & 127;
    int tid = threadIdx.x, wave = tid >> 6, lane = tid & 63;
    int lr = lane & 15, lg = lane >> 4;
    const float* xp = x + (size_t)n * CTV + t * V_;
    float* outp = out + (size_t)n * CTV + t * V_;
    float* mybins = bins + (blockIdx.x & (NCOPY - 1)) * 512;
    const f32x4 zacc = {0.f, 0.f, 0.f, 0.f};
    const bf16x8 zero8 = {0, 0, 0, 0, 0, 0, 0, 0};
    int myTiles = (wave < 4) ? 4 : 3;

    float b2s[4] = {0.f, 0.f, 0.f, 0.f};
    if (wave < 4) {
        #pragma unroll
        for (int i2 = 0; i2 < 4; ++i2)
            b2s[i2] = bias2sum[wave * 16 + lg * 4 + i2];
    }

    // ---- staging: register-ILP prefetch then LDS writes (round-9 pattern) ----
    {
        float xv[13], sc[13];
        #pragma unroll
        for (int j = 0; j < 13; ++j) {
            int i = tid + j * 512;
            if (i < 6400) {
                int c = i / 25, v = i - c * 25;
                xv[j] = xp[c * TV + v];
                sc[j] = a_scale[i];
            }
        }
        #pragma unroll
        for (int j = 0; j < 13; ++j) {
            int i = tid + j * 512;
            if (i < 6400) {
                int c = i / 25, v = i - c * 25;
                int off = bswz(v, c);
                Braw[off] = f2b(xv[j]);
                Bxn[off]  = f2b(xv[j] * sc[j]);
            }
        }
        for (int i = tid; i < 448; i += 512) {
            int v = 25 + (i >> 6), cz = (i & 63) * 4;
            u16x4 z4 = {0, 0, 0, 0};
            *(u16x4*)(Braw + v * 256 + cz) = z4;
            *(u16x4*)(Bxn + v * 256 + cz) = z4;
        }
    }
    __syncthreads();   // B1

    // ---- MERGED GEMM1: pq/pk (Braw) + q/k/g/v (Bxn), kk-outer, one loop ----
    f32x4 accP[2];
    accP[0] = zacc; accP[1] = zacc;
    f32x4 acc[4][2];
    #pragma unroll
    for (int i = 0; i < 4; ++i) { acc[i][0] = zacc; acc[i][1] = zacc; }
    #pragma unroll
    for (int kk = 0; kk < 8; ++kk) {
        int k0 = kk * 32 + lg * 8;
        int oct = (((k0 >> 3) ^ (lr & 7)) << 3);
        bf16x8 br0 = LD8(Braw + lr * 256 + oct);
        bf16x8 br1 = LD8(Braw + (16 + lr) * 256 + oct);
        bf16x8 bx0 = LD8(Bxn + lr * 256 + oct);
        bf16x8 bx1 = LD8(Bxn + (16 + lr) * 256 + oct);
        bf16x8 ap = LD8(Wq + (wave * 16 + lr) * 256 + k0);
        accP[0] = MFMA16(ap, br0, accP[0]);
        accP[1] = MFMA16(ap, br1, accP[1]);
        #pragma unroll
        for (int tt = 0; tt < 4; ++tt) {
            if (tt < myTiles) {
                int mt = wave + tt * 8;
                bf16x8 a = LD8(Wq + (mt * 16 + lr) * 256 + k0);
                acc[tt][0] = MFMA16(a, bx0, acc[tt][0]);
                acc[tt][1] = MFMA16(a, bx1, acc[tt][1]);
            }
        }
    }

    // ---- epilogues to region Z (safe pre-barrier): pq/pk + q/k/g; V deferred ----
    {
        int rb = wave * 16 + lg * 4;            // pq/pk rows 0..127
        u16x4 r0, r1;
        #pragma unroll
        for (int i2 = 0; i2 < 4; ++i2) {
            int r = rb + i2;
            r0[i2] = f2b(accP[0][i2] + peproj[r * 25 + lr]);
            r1[i2] = (lr < 9) ? f2b(accP[1][i2] + peproj[r * 25 + 16 + lr]) : (ushort)0;
        }
        *(u16x4*)(qkvT + qtswz(lr, 192 + rb)) = r0;
        *(u16x4*)(qkvT + qtswz(16 + lr, 192 + rb)) = r1;
    }
    f32x4 accV[2][2];
    int vIdx = 0;
    #pragma unroll
    for (int tt = 0; tt < 4; ++tt) {
        if (tt < myTiles) {
            int mt = wave + tt * 8;
            int ob = mt * 16 + lg * 4;
            if (mt < 4) {
                u16x4 r0, r1;
                #pragma unroll
                for (int i2 = 0; i2 < 4; ++i2) {
                    int o = ob + i2;
                    float cs = acc[tt][0][i2] + ((lr < 9) ? acc[tt][1][i2] : 0.f);
                    #pragma unroll
                    for (int mm = 1; mm < 16; mm <<= 1)
                        cs += __shfl_xor(cs, mm, 64);
                    float mu = (cs + b2s[i2]) * 0.04f;
                    ushort mur = f2b(mu);
                    float muf = b2f(mur);
                    r0[i2] = f2b(acc[tt][0][i2] + bias2[o * 25 + lr] - muf);
                    r1[i2] = (lr < 9)
                        ? f2b(acc[tt][1][i2] + bias2[o * 25 + 16 + lr] - muf)
                        : (ushort)0;
                    if (lr == 0) qmub[o] = mur;
                }
                *(u16x4*)(qkvT + qtswz(lr, ob)) = r0;
                *(u16x4*)(qkvT + qtswz(16 + lr, ob)) = r1;
            } else if (mt < 12) {
                u16x4 r0, r1;
                #pragma unroll
                for (int i2 = 0; i2 < 4; ++i2) {
                    int o = ob + i2;
                    r0[i2] = f2b(acc[tt][0][i2] + bias2[o * 25 + lr]);
                    r1[i2] = (lr < 9)
                        ? f2b(acc[tt][1][i2] + bias2[o * 25 + 16 + lr])
                        : (ushort)0;
                }
                *(u16x4*)(qkvT + qtswz(lr, ob)) = r0;
                *(u16x4*)(qkvT + qtswz(16 + lr, ob)) = r1;
            } else {
                accV[vIdx][0] = acc[tt][0];
                accV[vIdx][1] = acc[tt][1];
                ++vIdx;
            }
        }
    }
    __syncthreads();   // B2: all Braw/Bxn reads + Z writes done

    // ---- V epilogue -> qkvV (region X, Braw dead) ----
    {
        int vi = 0;
        #pragma unroll
        for (int tt = 0; tt < 4; ++tt) {
            if (tt < myTiles) {
                int mt = wave + tt * 8;
                if (mt >= 12) {
                    int ob = mt * 16 + lg * 4;
                    #pragma unroll
                    for (int i2 = 0; i2 < 4; ++i2) {
                        int o = ob + i2;
                        int e = o - 192;
                        qkvV[qvswz(e, lr)] = f2b(accV[vi][0][i2] + bias2[o * 25 + lr]);
                        qkvV[qvswz(e, 16 + lr)] = (lr < 9)
                            ? f2b(accV[vi][1][i2] + bias2[o * 25 + 16 + lr])
                            : (ushort)0;
                    }
                    ++vi;
                }
            }
        }
    }

    // ---- weights phase (wave = head h) ----
    int h = wave;
    bf16x8 mu8 = LD8(qmub + h * 8);
    bf16x8 aP1[2], aP2[2], bP1[2], bP2[2];
    #pragma unroll
    for (int mi = 0; mi < 2; ++mi) {
        int row = mi * 16 + lr, sx = row & 7;
        const ushort* rp = qkvT + row * 320;
        aP1[mi] = (lg == 0) ? LD8(rp + ((h ^ sx) << 3))
                : (lg == 1) ? LD8(rp + (((24 + h) ^ sx) << 3)) : zero8;
        aP2[mi] = (lg == 0) ? LD8(rp + (((24 + h) ^ sx) << 3))
                : (lg == 1) ? mu8 : zero8;
        bP1[mi] = (lg == 0) ? LD8(rp + (((8 + h) ^ sx) << 3))
                : (lg == 1) ? LD8(rp + (((32 + h) ^ sx) << 3)) : zero8;
        bP2[mi] = (lg == 0) ? LD8(rp + (((32 + h) ^ sx) << 3))
                : (lg == 1) ? LD8(rp + (((16 + h) ^ sx) << 3)) : zero8;
    }
    f32x4 p1[2][2], p2[2][2];
    #pragma unroll
    for (int mi = 0; mi < 2; ++mi)
        #pragma unroll
        for (int ni = 0; ni < 2; ++ni) {
            p1[mi][ni] = MFMA16(aP1[mi], bP1[ni], zacc);
            p2[mi][ni] = MFMA16(aP2[mi], bP2[ni], zacc);
        }
    __syncthreads();   // B3: qkvT dead -> pbuf may overwrite Z; qkvV writes visible

    // ---- skip prefetch (hidden under tanh + attn phases) ----
    float sk0[2][4], sk1[2][4];
    #pragma unroll
    for (int tt = 0; tt < 2; ++tt)
        #pragma unroll
        for (int i2 = 0; i2 < 4; ++i2) {
            int o = (wave + tt * 8) * 16 + lg * 4 + i2;
            sk0[tt][i2] = xp[o * TV + lr];
            sk1[tt][i2] = (lr < 9) ? xp[o * TV + 16 + lr] : 0.f;
        }

    // ---- pbuf[h][v][w] = tanh(P1) + tanh(P2) ----
    #pragma unroll
    for (int mi = 0; mi < 2; ++mi)
        #pragma unroll
        for (int ni = 0; ni < 2; ++ni) {
            int w = ni * 16 + lr;
            #pragma unroll
            for (int i2 = 0; i2 < 4; ++i2) {
                int v = mi * 16 + lg * 4 + i2;
                float tw = tanh_fast(p1[mi][ni][i2]) + tanh_fast(p2[mi][ni][i2]);
                pbuf[(h * 32 + v) * 40 + w] = (w < 25) ? f2b(tw) : (ushort)0;
            }
        }

    // ---- attn: weights x V -> aT[v][e] ----
    {
        bf16x8 aw[2], bv[2];
        #pragma unroll
        for (int mi = 0; mi < 2; ++mi)
            aw[mi] = LD8(pbuf + (h * 32 + mi * 16 + lr) * 40 + lg * 8);
        #pragma unroll
        for (int ni = 0; ni < 2; ++ni) {
            int e = h * 32 + ni * 16 + lr;
            bv[ni] = LD8(qkvV + e * 32 + ((lg ^ (e & 3)) << 3));
        }
        f32x4 at_[2][2];
        #pragma unroll
        for (int mi = 0; mi < 2; ++mi)
            #pragma unroll
            for (int ni = 0; ni < 2; ++ni)
                at_[mi][ni] = MFMA16(aw[mi], bv[ni], zacc);
        #pragma unroll
        for (int mi = 0; mi < 2; ++mi)
            #pragma unroll
            for (int ni = 0; ni < 2; ++ni)
                #pragma unroll
                for (int i2 = 0; i2 < 4; ++i2) {
                    int v = mi * 16 + lg * 4 + i2;
                    int e = h * 32 + ni * 16 + lr;
                    if (v < 25) aT[bswz(v, e)] = f2b(at_[mi][ni][i2]);
                }
    }
    __syncthreads();   // B5: aT complete

    // ---- GEMM2 + store + bn2 partials ----
    #pragma unroll
    for (int tt = 0; tt < 2; ++tt) {
        int o0 = (wave + tt * 8) * 16;
        const ushort* Arow = Wa + (o0 + lr) * 256;
        f32x4 a0 = zacc, a1 = zacc;
        #pragma unroll
        for (int kk = 0; kk < 8; ++kk) {
            int k0 = kk * 32 + lg * 8;
            int oct = (((k0 >> 3) ^ (lr & 7)) << 3);
            bf16x8 a  = LD8(Arow + k0);
            bf16x8 b0 = LD8(aT + lr * 256 + oct);
            bf16x8 b1 = LD8(aT + (16 + lr) * 256 + oct);
            a0 = MFMA16(a, b0, a0);
            a1 = MFMA16(a, b1, a1);
        }
        #pragma unroll
        for (int i2 = 0; i2 < 4; ++i2) {
            int o = o0 + lg * 4 + i2;
            float bias = attn_b[o];
            float v0 = a0[i2] + bias + sk0[tt][i2];
            outp[o * TV + lr] = v0;
            float v1 = 0.f;
            if (lr < 9) {
                v1 = a1[i2] + bias + sk1[tt][i2];
                outp[o * TV + 16 + lr] = v1;
            }
            float cs = v0 + v1, cq = v0 * v0 + v1 * v1;
            #pragma unroll
            for (int mm = 1; mm < 16; mm <<= 1) {
                cs += __shfl_xor(cs, mm, 64);
                cq += __shfl_xor(cq, mm, 64);
            }
            if (lr == 0) {
                atomicAdd(&mybins[o], cs);
                atomicAdd(&mybins[256 + o], cq);
            }
        }
    }
}

// ---------------- bn2 final + apply ----------------
__global__ void bn2_final_kernel(const float* __restrict__ bins,
                                 const float* __restrict__ gamma,
                                 const float* __restrict__ beta,
                                 float* __restrict__ scale,
                                 float* __restrict__ shift) {
    int c = threadIdx.x;
    float s = 0.f, q = 0.f;
    for (int cp = 0; cp < NCOPY; ++cp) {
        s += bins[cp * 512 + c];
        q += bins[cp * 512 + 256 + c];
    }
    float inv = 1.0f / (float)(N_ * TV);
    float mean = s * inv;
    float var = q * inv - mean * mean;
    float sc = rsqrtf(var + EPS_) * gamma[c];
    scale[c] = sc;
    shift[c] = beta[c] - mean * sc;
}

__global__ void bn2_apply_kernel(float4* __restrict__ y,
                                 const float* __restrict__ scale,
                                 const float* __restrict__ shift) {
    const int total4 = N_ * CTV / 4;
    for (int i = blockIdx.x * blockDim.x + threadIdx.x; i < total4;
         i += gridDim.x * blockDim.x) {
        int c = (i / (TV / 4)) & 255;
        float4 v = y[i];
        float sc = scale[c], sh = shift[c];
        v.x = fmaxf(fmaf(v.x, sc, sh), 0.f);
        v.y = fmaxf(fmaf(v.y, sc, sh), 0.f);
        v.z = fmaxf(fmaf(v.z, sc, sh), 0.f);
        v.w = fmaxf(fmaf(v.w, sc, sh), 0.f);
        y[i] = v;
    }
}

extern "C" void kernel_launch(void* const* d_in, const int* in_sizes, int n_in,
                              void* d_out, int out_size, void* d_ws, size_t ws_size,
                              hipStream_t stream) {
    const float* x      = (const float*)d_in[0];
    const float* qkv_w  = (const float*)d_in[1];
    const float* qkv_b  = (const float*)d_in[2];
    const float* attn_w = (const float*)d_in[3];
    const float* attn_b = (const float*)d_in[4];
    const float* dbn_g  = (const float*)d_in[5];
    const float* dbn_b  = (const float*)d_in[6];
    const float* bn_g   = (const float*)d_in[7];
    const float* bn_b   = (const float*)d_in[8];
    float* out = (float*)d_out;

    char* ws = (char*)d_ws;
    ushort* Wq       = (ushort*)ws;                 // 229376 B
    ushort* Wa       = (ushort*)(ws + 229376);      // 131072 B
    float*  pe       = (float*)(ws + 360448);       // 25600 B
    float*  a_scale  = (float*)(ws + 386048);       // 25600 B
    float*  a_shift  = (float*)(ws + 411648);       // 25600 B
    float*  bias2    = (float*)(ws + 437248);       // 44800 B
    float*  peproj   = (float*)(ws + 482048);       // 12800 B
    float*  bias2sum = (float*)(ws + 494848);       // 256 B
    float*  bins     = (float*)(ws + 495104);       // 131072 B
    float*  bn2_sc   = (float*)(ws + 626176);       // 1024 B
    float*  bn2_sh   = (float*)(ws + 627200);       // 1024 B

    prep_kernel<<<256, 256, 0, stream>>>(qkv_w, attn_w, Wq, Wa, pe, bins);
    dbn_kernel<<<C_, 1024, 0, stream>>>(x, dbn_g, dbn_b, a_scale, a_shift);
    mkbias_kernel<<<57, 256, 0, stream>>>(Wq, qkv_b, a_shift, pe, bias2, peproj);
    b2sum_kernel<<<1, 64, 0, stream>>>(bias2, bias2sum);
    fused_kernel<<<N_ * T_, 512, 0, stream>>>(x, Wq, bias2, peproj, a_scale,
                                              bias2sum, Wa, attn_b, out, bins);
    bn2_final_kernel<<<1, 256, 0, stream>>>(bins, bn_g, bn_b, bn2_sc, bn2_sh);
    bn2_apply_kernel<<<4096, 256, 0, stream>>>((float4*)out, bn2_sc, bn2_sh);
}

// Round 15
// 351.824 us; speedup vs baseline: 1.7032x; 1.0899x over previous
//
#include <hip/hip_runtime.h>
#include <hip/hip_bf16.h>
#include <math.h>

#define N_   32
#define C_   256
#define T_   128
#define V_   25
#define CTV  (C_ * T_ * V_)   // 819200
#define TV   (T_ * V_)        // 3200
#define EPS_ 1e-5f
#define S_Q  0.35355339059327373f
#define NCOPY 64

typedef __attribute__((ext_vector_type(8))) short bf16x8;
typedef __attribute__((ext_vector_type(4))) float f32x4;
typedef __attribute__((ext_vector_type(4))) unsigned short u16x4;

__device__ inline ushort f2b(float f) {
    __hip_bfloat16 h = __float2bfloat16(f);
    return *reinterpret_cast<ushort*>(&h);
}
__device__ inline float b2f(ushort u) {
    __hip_bfloat16 h;
    *reinterpret_cast<ushort*>(&h) = u;
    return __bfloat162float(h);
}
__device__ inline float tanh_fast(float x) {
    float xc = fminf(fmaxf(x, -12.f), 12.f);
    float e = __expf(xc + xc);
    return (e - 1.f) * __builtin_amdgcn_rcpf(e + 1.f);
}
#define LD8(p) (*(const bf16x8*)(p))
#define MFMA16(a, b, c) __builtin_amdgcn_mfma_f32_16x16x32_bf16(a, b, c, 0, 0, 0)

// qkvT (swizzled, [32 v][320]): cols 0..63 q(centered) | 64..127 k | 128..191 g | 192..255 pq | 256..319 pk
__device__ inline int qtswz(int v, int col) {
    return v * 320 + ((((col >> 3)) ^ (v & 7)) << 3) + (col & 7);
}
__device__ inline int qvswz(int e, int w) {     // qkvV [256][32]
    return e * 32 + (((w >> 3) ^ (e & 3)) << 3) + (w & 7);
}
__device__ inline int bswz(int v, int c) {      // B tiles / aT [32][256]
    return v * 256 + ((((c >> 3) ^ (v & 7)) << 3) | (c & 7));
}

// ---------------- prep ----------------
__global__ void prep_kernel(const float* __restrict__ qkv_w,
                            const float* __restrict__ attn_w,
                            ushort* __restrict__ Wq, ushort* __restrict__ Wa,
                            float* __restrict__ pe, float* __restrict__ bins) {
    int idx = blockIdx.x * blockDim.x + threadIdx.x;
    int stride = gridDim.x * blockDim.x;
    for (int i = idx; i < 448 * 256; i += stride) {
        float w = qkv_w[i];
        if (i < 64 * 256) w *= S_Q;
        Wq[i] = f2b(w);
    }
    for (int i = idx; i < 256 * 256; i += stride) Wa[i] = f2b(attn_w[i]);
    for (int i = idx; i < C_ * V_; i += stride) {
        int c = i / V_, v = i - c * V_;
        int j2 = c & ~1;
        float ang = (float)v * expf(-logf(10000.0f) * (float)j2 / (float)C_);
        pe[i] = (c & 1) ? cosf(ang) : sinf(ang);
    }
    for (int i = idx; i < NCOPY * 512; i += stride) bins[i] = 0.f;
}

// ---------------- data_bn stats ----------------
__global__ __launch_bounds__(1024) void dbn_kernel(const float* __restrict__ x,
                                                   const float* __restrict__ gamma,
                                                   const float* __restrict__ beta,
                                                   float* __restrict__ a_scale,
                                                   float* __restrict__ a_shift) {
    __shared__ float pgS[32][25], pgQ[32][25];
    int c = blockIdx.x;
    int tid = threadIdx.x, g = tid >> 5, l = tid & 31;
    float s = 0.f, s2 = 0.f;
    if (l < 25) {
        const float* base = x + (size_t)g * CTV + c * TV + l;
        #pragma unroll 8
        for (int t = 0; t < 128; ++t) {
            float v = base[t * 25];
            s += v; s2 += v * v;
        }
        pgS[g][l] = s; pgQ[g][l] = s2;
    }
    __syncthreads();
    if (tid < 25) {
        float S = 0.f, Q = 0.f;
        #pragma unroll
        for (int g2 = 0; g2 < 32; ++g2) { S += pgS[g2][tid]; Q += pgQ[g2][tid]; }
        float inv = 1.0f / 4096.0f;
        float mean = S * inv, var = Q * inv - mean * mean;
        int f = c * 25 + tid;
        float sc = rsqrtf(var + EPS_) * gamma[f];
        a_scale[f] = sc;
        a_shift[f] = beta[f] - mean * sc;
    }
}

// ---------------- bias2 / peproj ----------------
__global__ void mkbias_kernel(const ushort* __restrict__ Wq,
                              const float* __restrict__ qkv_b,
                              const float* __restrict__ a_shift,
                              const float* __restrict__ pe,
                              float* __restrict__ bias2, float* __restrict__ peproj) {
    int id = blockIdx.x * 256 + threadIdx.x;
    if (id < 11200) {
        int o = id / 25, v = id - o * 25;
        float acc = qkv_b[o] * (o < 64 ? S_Q : 1.f);
        for (int c = 0; c < 256; ++c)
            acc = fmaf(b2f(Wq[o * 256 + c]), a_shift[c * 25 + v], acc);
        bias2[id] = acc;
    } else if (id < 14400) {
        int id2 = id - 11200;
        int r = id2 / 25, v = id2 - r * 25;
        float acc = qkv_b[r] * (r < 64 ? S_Q : 1.f);
        for (int c = 0; c < 256; ++c)
            acc = fmaf(b2f(Wq[r * 256 + c]), pe[c * 25 + v], acc);
        peproj[id2] = acc;
    }
}

__global__ void b2sum_kernel(const float* __restrict__ bias2,
                             float* __restrict__ bias2sum) {
    int o = threadIdx.x;   // 64
    float s = 0.f;
    #pragma unroll
    for (int v = 0; v < 25; ++v) s += bias2[o * 25 + v];
    bias2sum[o] = s;
}

// ---------------- fused per-token kernel (round-9 + dedicated qkvV, B1.5 deleted) ----
// X [0,16384)      Braw (dead after B2)
// Y [16384,32768)  Bxn  -> aT
// Z [32768,53248)  qkvT -> pbuf
// W [53248,69632)  qkvV (dedicated)
// [69632,69760)    qmub
__global__ __launch_bounds__(512, 4) void fused_kernel(
        const float* __restrict__ x,
        const ushort* __restrict__ Wq,
        const float* __restrict__ bias2, const float* __restrict__ peproj,
        const float* __restrict__ a_scale, const float* __restrict__ bias2sum,
        const ushort* __restrict__ Wa, const float* __restrict__ attn_b,
        float* __restrict__ out, float* __restrict__ bins) {
    __shared__ __align__(16) char smem[69760];
    ushort* Braw = (ushort*)smem;
    ushort* Bxn  = (ushort*)(smem + 16384);
    ushort* qkvT = (ushort*)(smem + 32768);
    ushort* qkvV = (ushort*)(smem + 53248);
    ushort* aT   = (ushort*)(smem + 16384);
    ushort* pbuf = (ushort*)(smem + 32768);
    ushort* qmub = (ushort*)(smem + 69632);

    int n = blockIdx.x >> 7, t = blockIdx.x & 127;
    int tid = threadIdx.x, wave = tid >> 6, lane = tid & 63;
    int lr = lane & 15, lg = lane >> 4;
    const float* xp = x + (size_t)n * CTV + t * V_;
    float* outp = out + (size_t)n * CTV + t * V_;
    float* mybins = bins + (blockIdx.x & (NCOPY - 1)) * 512;
    const f32x4 zacc = {0.f, 0.f, 0.f, 0.f};
    const bf16x8 zero8 = {0, 0, 0, 0, 0, 0, 0, 0};

    float b2s[4] = {0.f, 0.f, 0.f, 0.f};
    if (wave < 4) {
        #pragma unroll
        for (int i2 = 0; i2 < 4; ++i2)
            b2s[i2] = bias2sum[wave * 16 + lg * 4 + i2];
    }

    // ---- staging: register-ILP prefetch then LDS writes ----
    {
        float xv[13], sc[13];
        #pragma unroll
        for (int j = 0; j < 13; ++j) {
            int i = tid + j * 512;
            if (i < 6400) {
                int c = i / 25, v = i - c * 25;
                xv[j] = xp[c * TV + v];
                sc[j] = a_scale[i];
            }
        }
        #pragma unroll
        for (int j = 0; j < 13; ++j) {
            int i = tid + j * 512;
            if (i < 6400) {
                int c = i / 25, v = i - c * 25;
                int off = bswz(v, c);
                Braw[off] = f2b(xv[j]);
                Bxn[off]  = f2b(xv[j] * sc[j]);
            }
        }
        for (int i = tid; i < 448; i += 512) {
            int v = 25 + (i >> 6), cz = (i & 63) * 4;
            u16x4 z4 = {0, 0, 0, 0};
            *(u16x4*)(Braw + v * 256 + cz) = z4;
            *(u16x4*)(Bxn + v * 256 + cz) = z4;
        }
    }
    __syncthreads();   // B1

    // ---- pq/pk tile (1 per wave), reads Braw; epilogue -> qkvT (Z) ----
    {
        const ushort* Arow = Wq + (wave * 16 + lr) * 256;
        f32x4 a0 = zacc, a1 = zacc;
        #pragma unroll
        for (int kk = 0; kk < 8; ++kk) {
            int k0 = kk * 32 + lg * 8;
            int oct = (((k0 >> 3) ^ (lr & 7)) << 3);
            bf16x8 a  = LD8(Arow + k0);
            bf16x8 b0 = LD8(Braw + lr * 256 + oct);
            bf16x8 b1 = LD8(Braw + (16 + lr) * 256 + oct);
            a0 = MFMA16(a, b0, a0);
            a1 = MFMA16(a, b1, a1);
        }
        int rb = wave * 16 + lg * 4;
        u16x4 r0, r1;
        #pragma unroll
        for (int i2 = 0; i2 < 4; ++i2) {
            int r = rb + i2;
            r0[i2] = f2b(a0[i2] + peproj[r * 25 + lr]);
            r1[i2] = (lr < 9) ? f2b(a1[i2] + peproj[r * 25 + 16 + lr]) : (ushort)0;
        }
        *(u16x4*)(qkvT + qtswz(lr, 192 + rb)) = r0;
        *(u16x4*)(qkvT + qtswz(16 + lr, 192 + rb)) = r1;
    }
    // (no barrier: qkvV is a dedicated region; no one reads Z/W yet)

    // ---- q/k/g/v tiles (kk-outer, shared B frags); immediate epilogues ----
    {
        int myTiles = (wave < 4) ? 4 : 3;
        f32x4 acc[4][2];
        #pragma unroll
        for (int i = 0; i < 4; ++i) { acc[i][0] = zacc; acc[i][1] = zacc; }
        #pragma unroll
        for (int kk = 0; kk < 8; ++kk) {
            int k0 = kk * 32 + lg * 8;
            int oct = (((k0 >> 3) ^ (lr & 7)) << 3);
            bf16x8 b0 = LD8(Bxn + lr * 256 + oct);
            bf16x8 b1 = LD8(Bxn + (16 + lr) * 256 + oct);
            #pragma unroll
            for (int tt = 0; tt < 4; ++tt) {
                if (tt < myTiles) {
                    int mt = wave + tt * 8;
                    bf16x8 a = LD8(Wq + (mt * 16 + lr) * 256 + k0);
                    acc[tt][0] = MFMA16(a, b0, acc[tt][0]);
                    acc[tt][1] = MFMA16(a, b1, acc[tt][1]);
                }
            }
        }
        #pragma unroll
        for (int tt = 0; tt < 4; ++tt) {
            if (tt < myTiles) {
                int mt = wave + tt * 8;
                int ob = mt * 16 + lg * 4;
                if (mt < 4) {
                    u16x4 r0, r1;
                    #pragma unroll
                    for (int i2 = 0; i2 < 4; ++i2) {
                        int o = ob + i2;
                        float cs = acc[tt][0][i2] + ((lr < 9) ? acc[tt][1][i2] : 0.f);
                        #pragma unroll
                        for (int mm = 1; mm < 16; mm <<= 1)
                            cs += __shfl_xor(cs, mm, 64);
                        float mu = (cs + b2s[i2]) * 0.04f;
                        ushort mur = f2b(mu);
                        float muf = b2f(mur);
                        r0[i2] = f2b(acc[tt][0][i2] + bias2[o * 25 + lr] - muf);
                        r1[i2] = (lr < 9)
                            ? f2b(acc[tt][1][i2] + bias2[o * 25 + 16 + lr] - muf)
                            : (ushort)0;
                        if (lr == 0) qmub[o] = mur;
                    }
                    *(u16x4*)(qkvT + qtswz(lr, ob)) = r0;
                    *(u16x4*)(qkvT + qtswz(16 + lr, ob)) = r1;
                } else if (mt < 12) {
                    u16x4 r0, r1;
                    #pragma unroll
                    for (int i2 = 0; i2 < 4; ++i2) {
                        int o = ob + i2;
                        r0[i2] = f2b(acc[tt][0][i2] + bias2[o * 25 + lr]);
                        r1[i2] = (lr < 9)
                            ? f2b(acc[tt][1][i2] + bias2[o * 25 + 16 + lr])
                            : (ushort)0;
                    }
                    *(u16x4*)(qkvT + qtswz(lr, ob)) = r0;
                    *(u16x4*)(qkvT + qtswz(16 + lr, ob)) = r1;
                } else {
                    #pragma unroll
                    for (int i2 = 0; i2 < 4; ++i2) {
                        int o = ob + i2;
                        int e = o - 192;
                        qkvV[qvswz(e, lr)] = f2b(acc[tt][0][i2] + bias2[o * 25 + lr]);
                        qkvV[qvswz(e, 16 + lr)] = (lr < 9)
                            ? f2b(acc[tt][1][i2] + bias2[o * 25 + 16 + lr])
                            : (ushort)0;
                    }
                }
            }
        }
    }
    __syncthreads();   // B2: all Braw/Bxn reads + qkvT/qkvV writes done

    // ---- weights phase (wave = head h) ----
    int h = wave;
    bf16x8 mu8 = LD8(qmub + h * 8);
    bf16x8 aP1[2], aP2[2], bP1[2], bP2[2];
    #pragma unroll
    for (int mi = 0; mi < 2; ++mi) {
        int row = mi * 16 + lr, sx = row & 7;
        const ushort* rp = qkvT + row * 320;
        aP1[mi] = (lg == 0) ? LD8(rp + ((h ^ sx) << 3))
                : (lg == 1) ? LD8(rp + (((24 + h) ^ sx) << 3)) : zero8;
        aP2[mi] = (lg == 0) ? LD8(rp + (((24 + h) ^ sx) << 3))
                : (lg == 1) ? mu8 : zero8;
        bP1[mi] = (lg == 0) ? LD8(rp + (((8 + h) ^ sx) << 3))
                : (lg == 1) ? LD8(rp + (((32 + h) ^ sx) << 3)) : zero8;
        bP2[mi] = (lg == 0) ? LD8(rp + (((32 + h) ^ sx) << 3))
                : (lg == 1) ? LD8(rp + (((16 + h) ^ sx) << 3)) : zero8;
    }
    f32x4 p1[2][2], p2[2][2];
    #pragma unroll
    for (int mi = 0; mi < 2; ++mi)
        #pragma unroll
        for (int ni = 0; ni < 2; ++ni) {
            p1[mi][ni] = MFMA16(aP1[mi], bP1[ni], zacc);
            p2[mi][ni] = MFMA16(aP2[mi], bP2[ni], zacc);
        }
    __syncthreads();   // B3: qkvT dead -> pbuf may overwrite Z

    // ---- pbuf[h][v][w] = tanh(P1) + tanh(P2) ----
    #pragma unroll
    for (int mi = 0; mi < 2; ++mi)
        #pragma unroll
        for (int ni = 0; ni < 2; ++ni) {
            int w = ni * 16 + lr;
            #pragma unroll
            for (int i2 = 0; i2 < 4; ++i2) {
                int v = mi * 16 + lg * 4 + i2;
                float tw = tanh_fast(p1[mi][ni][i2]) + tanh_fast(p2[mi][ni][i2]);
                pbuf[(h * 32 + v) * 40 + w] = (w < 25) ? f2b(tw) : (ushort)0;
            }
        }

    // ---- attn: weights x V -> aT[v][e] (aT aliases Bxn, dead since B2) ----
    {
        bf16x8 aw[2], bv[2];
        #pragma unroll
        for (int mi = 0; mi < 2; ++mi)
            aw[mi] = LD8(pbuf + (h * 32 + mi * 16 + lr) * 40 + lg * 8);
        #pragma unroll
        for (int ni = 0; ni < 2; ++ni) {
            int e = h * 32 + ni * 16 + lr;
            bv[ni] = LD8(qkvV + e * 32 + ((lg ^ (e & 3)) << 3));
        }
        f32x4 at_[2][2];
        #pragma unroll
        for (int mi = 0; mi < 2; ++mi)
            #pragma unroll
            for (int ni = 0; ni < 2; ++ni)
                at_[mi][ni] = MFMA16(aw[mi], bv[ni], zacc);
        #pragma unroll
        for (int mi = 0; mi < 2; ++mi)
            #pragma unroll
            for (int ni = 0; ni < 2; ++ni)
                #pragma unroll
                for (int i2 = 0; i2 < 4; ++i2) {
                    int v = mi * 16 + lg * 4 + i2;
                    int e = h * 32 + ni * 16 + lr;
                    if (v < 25) aT[bswz(v, e)] = f2b(at_[mi][ni][i2]);
                }
    }
    __syncthreads();   // B5: aT complete

    // ---- GEMM2 + store + bn2 partials ----
    float sk0[2][4], sk1[2][4];
    #pragma unroll
    for (int tt = 0; tt < 2; ++tt)
        #pragma unroll
        for (int i2 = 0; i2 < 4; ++i2) {
            int o = (wave + tt * 8) * 16 + lg * 4 + i2;
            sk0[tt][i2] = xp[o * TV + lr];
            sk1[tt][i2] = (lr < 9) ? xp[o * TV + 16 + lr] : 0.f;
        }
    #pragma unroll
    for (int tt = 0; tt < 2; ++tt) {
        int o0 = (wave + tt * 8) * 16;
        const ushort* Arow = Wa + (o0 + lr) * 256;
        f32x4 a0 = zacc, a1 = zacc;
        #pragma unroll
        for (int kk = 0; kk < 8; ++kk) {
            int k0 = kk * 32 + lg * 8;
            int oct = (((k0 >> 3) ^ (lr & 7)) << 3);
            bf16x8 a  = LD8(Arow + k0);
            bf16x8 b0 = LD8(aT + lr * 256 + oct);
            bf16x8 b1 = LD8(aT + (16 + lr) * 256 + oct);
            a0 = MFMA16(a, b0, a0);
            a1 = MFMA16(a, b1, a1);
        }
        #pragma unroll
        for (int i2 = 0; i2 < 4; ++i2) {
            int o = o0 + lg * 4 + i2;
            float bias = attn_b[o];
            float v0 = a0[i2] + bias + sk0[tt][i2];
            outp[o * TV + lr] = v0;
            float v1 = 0.f;
            if (lr < 9) {
                v1 = a1[i2] + bias + sk1[tt][i2];
                outp[o * TV + 16 + lr] = v1;
            }
            float cs = v0 + v1, cq = v0 * v0 + v1 * v1;
            #pragma unroll
            for (int mm = 1; mm < 16; mm <<= 1) {
                cs += __shfl_xor(cs, mm, 64);
                cq += __shfl_xor(cq, mm, 64);
            }
            if (lr == 0) {
                atomicAdd(&mybins[o], cs);
                atomicAdd(&mybins[256 + o], cq);
            }
        }
    }
}

// ---------------- bn2 final + apply ----------------
__global__ void bn2_final_kernel(const float* __restrict__ bins,
                                 const float* __restrict__ gamma,
                                 const float* __restrict__ beta,
                                 float* __restrict__ scale,
                                 float* __restrict__ shift) {
    int c = threadIdx.x;
    float s = 0.f, q = 0.f;
    for (int cp = 0; cp < NCOPY; ++cp) {
        s += bins[cp * 512 + c];
        q += bins[cp * 512 + 256 + c];
    }
    float inv = 1.0f / (float)(N_ * TV);
    float mean = s * inv;
    float var = q * inv - mean * mean;
    float sc = rsqrtf(var + EPS_) * gamma[c];
    scale[c] = sc;
    shift[c] = beta[c] - mean * sc;
}

__global__ void bn2_apply_kernel(float4* __restrict__ y,
                                 const float* __restrict__ scale,
                                 const float* __restrict__ shift) {
    const int total4 = N_ * CTV / 4;
    for (int i = blockIdx.x * blockDim.x + threadIdx.x; i < total4;
         i += gridDim.x * blockDim.x) {
        int c = (i / (TV / 4)) & 255;
        float4 v = y[i];
        float sc = scale[c], sh = shift[c];
        v.x = fmaxf(fmaf(v.x, sc, sh), 0.f);
        v.y = fmaxf(fmaf(v.y, sc, sh), 0.f);
        v.z = fmaxf(fmaf(v.z, sc, sh), 0.f);
        v.w = fmaxf(fmaf(v.w, sc, sh), 0.f);
        y[i] = v;
    }
}

extern "C" void kernel_launch(void* const* d_in, const int* in_sizes, int n_in,
                              void* d_out, int out_size, void* d_ws, size_t ws_size,
                              hipStream_t stream) {
    const float* x      = (const float*)d_in[0];
    const float* qkv_w  = (const float*)d_in[1];
    const float* qkv_b  = (const float*)d_in[2];
    const float* attn_w = (const float*)d_in[3];
    const float* attn_b = (const float*)d_in[4];
    const float* dbn_g  = (const float*)d_in[5];
    const float* dbn_b  = (const float*)d_in[6];
    const float* bn_g   = (const float*)d_in[7];
    const float* bn_b   = (const float*)d_in[8];
    float* out = (float*)d_out;

    char* ws = (char*)d_ws;
    ushort* Wq       = (ushort*)ws;                 // 229376 B
    ushort* Wa       = (ushort*)(ws + 229376);      // 131072 B
    float*  pe       = (float*)(ws + 360448);       // 25600 B
    float*  a_scale  = (float*)(ws + 386048);       // 25600 B
    float*  a_shift  = (float*)(ws + 411648);       // 25600 B
    float*  bias2    = (float*)(ws + 437248);       // 44800 B
    float*  peproj   = (float*)(ws + 482048);       // 12800 B
    float*  bias2sum = (float*)(ws + 494848);       // 256 B
    float*  bins     = (float*)(ws + 495104);       // 131072 B
    float*  bn2_sc   = (float*)(ws + 626176);       // 1024 B
    float*  bn2_sh   = (float*)(ws + 627200);       // 1024 B

    prep_kernel<<<256, 256, 0, stream>>>(qkv_w, attn_w, Wq, Wa, pe, bins);
    dbn_kernel<<<C_, 1024, 0, stream>>>(x, dbn_g, dbn_b, a_scale, a_shift);
    mkbias_kernel<<<57, 256, 0, stream>>>(Wq, qkv_b, a_shift, pe, bias2, peproj);
    b2sum_kernel<<<1, 64, 0, stream>>>(bias2, bias2sum);
    fused_kernel<<<N_ * T_, 512, 0, stream>>>(x, Wq, bias2, peproj, a_scale,
                                              bias2sum, Wa, attn_b, out, bins);
    bn2_final_kernel<<<1, 256, 0, stream>>>(bins, bn_g, bn_b, bn2_sc, bn2_sh);
    bn2_apply_kernel<<<4096, 256, 0, stream>>>((float4*)out, bn2_sc, bn2_sh);
}

// Round 16
// 343.811 us; speedup vs baseline: 1.7429x; 1.0233x over previous
//
#include <hip/hip_runtime.h>
#include <hip/hip_bf16.h>
#include <math.h>

#define N_   32
#define C_   256
#define T_   128
#define V_   25
#define CTV  (C_ * T_ * V_)   // 819200
#define TV   (T_ * V_)        // 3200
#define EPS_ 1e-5f
#define S_Q  0.35355339059327373f
#define NCOPY 64

typedef __attribute__((ext_vector_type(8))) short bf16x8;
typedef __attribute__((ext_vector_type(4))) float f32x4;
typedef __attribute__((ext_vector_type(4))) unsigned short u16x4;

__device__ inline ushort f2b(float f) {
    __hip_bfloat16 h = __float2bfloat16(f);
    return *reinterpret_cast<ushort*>(&h);
}
__device__ inline float b2f(ushort u) {
    __hip_bfloat16 h;
    *reinterpret_cast<ushort*>(&h) = u;
    return __bfloat162float(h);
}
__device__ inline float tanh_fast(float x) {
    float xc = fminf(fmaxf(x, -12.f), 12.f);
    float e = __expf(xc + xc);
    return (e - 1.f) * __builtin_amdgcn_rcpf(e + 1.f);
}
#define LD8(p) (*(const bf16x8*)(p))
#define MFMA16(a, b, c) __builtin_amdgcn_mfma_f32_16x16x32_bf16(a, b, c, 0, 0, 0)

// qkvT (swizzled, [32 v][320]): cols 0..63 q(centered) | 64..127 k | 128..191 g | 192..255 pq | 256..319 pk
__device__ inline int qtswz(int v, int col) {
    return v * 320 + ((((col >> 3)) ^ (v & 7)) << 3) + (col & 7);
}
__device__ inline int qvswz(int e, int w) {     // qkvV [256][32]
    return e * 32 + (((w >> 3) ^ (e & 3)) << 3) + (w & 7);
}
__device__ inline int bswz(int v, int c) {      // B tiles / aT [32][256]
    return v * 256 + ((((c >> 3) ^ (v & 7)) << 3) | (c & 7));
}

// ---------------- prep ----------------
__global__ void prep_kernel(const float* __restrict__ qkv_w,
                            const float* __restrict__ attn_w,
                            ushort* __restrict__ Wq, ushort* __restrict__ Wa,
                            float* __restrict__ pe, float* __restrict__ bins) {
    int idx = blockIdx.x * blockDim.x + threadIdx.x;
    int stride = gridDim.x * blockDim.x;
    for (int i = idx; i < 448 * 256; i += stride) {
        float w = qkv_w[i];
        if (i < 64 * 256) w *= S_Q;
        Wq[i] = f2b(w);
    }
    for (int i = idx; i < 256 * 256; i += stride) Wa[i] = f2b(attn_w[i]);
    for (int i = idx; i < C_ * V_; i += stride) {
        int c = i / V_, v = i - c * V_;
        int j2 = c & ~1;
        float ang = (float)v * expf(-logf(10000.0f) * (float)j2 / (float)C_);
        pe[i] = (c & 1) ? cosf(ang) : sinf(ang);
    }
    for (int i = idx; i < NCOPY * 512; i += stride) bins[i] = 0.f;
}

// ---------------- data_bn stats ----------------
__global__ __launch_bounds__(1024) void dbn_kernel(const float* __restrict__ x,
                                                   const float* __restrict__ gamma,
                                                   const float* __restrict__ beta,
                                                   float* __restrict__ a_scale,
                                                   float* __restrict__ a_shift) {
    __shared__ float pgS[32][25], pgQ[32][25];
    int c = blockIdx.x;
    int tid = threadIdx.x, g = tid >> 5, l = tid & 31;
    float s = 0.f, s2 = 0.f;
    if (l < 25) {
        const float* base = x + (size_t)g * CTV + c * TV + l;
        #pragma unroll 8
        for (int t = 0; t < 128; ++t) {
            float v = base[t * 25];
            s += v; s2 += v * v;
        }
        pgS[g][l] = s; pgQ[g][l] = s2;
    }
    __syncthreads();
    if (tid < 25) {
        float S = 0.f, Q = 0.f;
        #pragma unroll
        for (int g2 = 0; g2 < 32; ++g2) { S += pgS[g2][tid]; Q += pgQ[g2][tid]; }
        float inv = 1.0f / 4096.0f;
        float mean = S * inv, var = Q * inv - mean * mean;
        int f = c * 25 + tid;
        float sc = rsqrtf(var + EPS_) * gamma[f];
        a_scale[f] = sc;
        a_shift[f] = beta[f] - mean * sc;
    }
}

// ---------------- bias2 / peproj ----------------
__global__ void mkbias_kernel(const ushort* __restrict__ Wq,
                              const float* __restrict__ qkv_b,
                              const float* __restrict__ a_shift,
                              const float* __restrict__ pe,
                              float* __restrict__ bias2, float* __restrict__ peproj) {
    int id = blockIdx.x * 256 + threadIdx.x;
    if (id < 11200) {
        int o = id / 25, v = id - o * 25;
        float acc = qkv_b[o] * (o < 64 ? S_Q : 1.f);
        for (int c = 0; c < 256; ++c)
            acc = fmaf(b2f(Wq[o * 256 + c]), a_shift[c * 25 + v], acc);
        bias2[id] = acc;
    } else if (id < 14400) {
        int id2 = id - 11200;
        int r = id2 / 25, v = id2 - r * 25;
        float acc = qkv_b[r] * (r < 64 ? S_Q : 1.f);
        for (int c = 0; c < 256; ++c)
            acc = fmaf(b2f(Wq[r * 256 + c]), pe[c * 25 + v], acc);
        peproj[id2] = acc;
    }
}

__global__ void b2sum_kernel(const float* __restrict__ bias2,
                             float* __restrict__ bias2sum) {
    int o = threadIdx.x;   // 64
    float s = 0.f;
    #pragma unroll
    for (int v = 0; v < 25; ++v) s += bias2[o * 25 + v];
    bias2sum[o] = s;
}

// ---------------- fused per-token kernel (round-15 + bf16 y intermediate) ----------
// X [0,16384)      Braw (dead after B2)
// Y [16384,32768)  Bxn  -> aT
// Z [32768,53248)  qkvT -> pbuf
// W [53248,69632)  qkvV (dedicated)
// [69632,69760)    qmub
__global__ __launch_bounds__(512, 4) void fused_kernel(
        const float* __restrict__ x,
        const ushort* __restrict__ Wq,
        const float* __restrict__ bias2, const float* __restrict__ peproj,
        const float* __restrict__ a_scale, const float* __restrict__ bias2sum,
        const ushort* __restrict__ Wa, const float* __restrict__ attn_b,
        ushort* __restrict__ ybf, float* __restrict__ bins) {
    __shared__ __align__(16) char smem[69760];
    ushort* Braw = (ushort*)smem;
    ushort* Bxn  = (ushort*)(smem + 16384);
    ushort* qkvT = (ushort*)(smem + 32768);
    ushort* qkvV = (ushort*)(smem + 53248);
    ushort* aT   = (ushort*)(smem + 16384);
    ushort* pbuf = (ushort*)(smem + 32768);
    ushort* qmub = (ushort*)(smem + 69632);

    int n = blockIdx.x >> 7, t = blockIdx.x & 127;
    int tid = threadIdx.x, wave = tid >> 6, lane = tid & 63;
    int lr = lane & 15, lg = lane >> 4;
    const float* xp = x + (size_t)n * CTV + t * V_;
    ushort* yp = ybf + (size_t)n * CTV + t * V_;
    float* mybins = bins + (blockIdx.x & (NCOPY - 1)) * 512;
    const f32x4 zacc = {0.f, 0.f, 0.f, 0.f};
    const bf16x8 zero8 = {0, 0, 0, 0, 0, 0, 0, 0};

    float b2s[4] = {0.f, 0.f, 0.f, 0.f};
    if (wave < 4) {
        #pragma unroll
        for (int i2 = 0; i2 < 4; ++i2)
            b2s[i2] = bias2sum[wave * 16 + lg * 4 + i2];
    }

    // ---- staging: register-ILP prefetch then LDS writes ----
    {
        float xv[13], sc[13];
        #pragma unroll
        for (int j = 0; j < 13; ++j) {
            int i = tid + j * 512;
            if (i < 6400) {
                int c = i / 25, v = i - c * 25;
                xv[j] = xp[c * TV + v];
                sc[j] = a_scale[i];
            }
        }
        #pragma unroll
        for (int j = 0; j < 13; ++j) {
            int i = tid + j * 512;
            if (i < 6400) {
                int c = i / 25, v = i - c * 25;
                int off = bswz(v, c);
                Braw[off] = f2b(xv[j]);
                Bxn[off]  = f2b(xv[j] * sc[j]);
            }
        }
        for (int i = tid; i < 448; i += 512) {
            int v = 25 + (i >> 6), cz = (i & 63) * 4;
            u16x4 z4 = {0, 0, 0, 0};
            *(u16x4*)(Braw + v * 256 + cz) = z4;
            *(u16x4*)(Bxn + v * 256 + cz) = z4;
        }
    }
    __syncthreads();   // B1

    // ---- pq/pk tile (1 per wave), reads Braw; epilogue -> qkvT (Z) ----
    {
        const ushort* Arow = Wq + (wave * 16 + lr) * 256;
        f32x4 a0 = zacc, a1 = zacc;
        #pragma unroll
        for (int kk = 0; kk < 8; ++kk) {
            int k0 = kk * 32 + lg * 8;
            int oct = (((k0 >> 3) ^ (lr & 7)) << 3);
            bf16x8 a  = LD8(Arow + k0);
            bf16x8 b0 = LD8(Braw + lr * 256 + oct);
            bf16x8 b1 = LD8(Braw + (16 + lr) * 256 + oct);
            a0 = MFMA16(a, b0, a0);
            a1 = MFMA16(a, b1, a1);
        }
        int rb = wave * 16 + lg * 4;
        u16x4 r0, r1;
        #pragma unroll
        for (int i2 = 0; i2 < 4; ++i2) {
            int r = rb + i2;
            r0[i2] = f2b(a0[i2] + peproj[r * 25 + lr]);
            r1[i2] = (lr < 9) ? f2b(a1[i2] + peproj[r * 25 + 16 + lr]) : (ushort)0;
        }
        *(u16x4*)(qkvT + qtswz(lr, 192 + rb)) = r0;
        *(u16x4*)(qkvT + qtswz(16 + lr, 192 + rb)) = r1;
    }
    // (no barrier: qkvV is a dedicated region)

    // ---- q/k/g/v tiles (kk-outer, shared B frags); immediate epilogues ----
    {
        int myTiles = (wave < 4) ? 4 : 3;
        f32x4 acc[4][2];
        #pragma unroll
        for (int i = 0; i < 4; ++i) { acc[i][0] = zacc; acc[i][1] = zacc; }
        #pragma unroll
        for (int kk = 0; kk < 8; ++kk) {
            int k0 = kk * 32 + lg * 8;
            int oct = (((k0 >> 3) ^ (lr & 7)) << 3);
            bf16x8 b0 = LD8(Bxn + lr * 256 + oct);
            bf16x8 b1 = LD8(Bxn + (16 + lr) * 256 + oct);
            #pragma unroll
            for (int tt = 0; tt < 4; ++tt) {
                if (tt < myTiles) {
                    int mt = wave + tt * 8;
                    bf16x8 a = LD8(Wq + (mt * 16 + lr) * 256 + k0);
                    acc[tt][0] = MFMA16(a, b0, acc[tt][0]);
                    acc[tt][1] = MFMA16(a, b1, acc[tt][1]);
                }
            }
        }
        #pragma unroll
        for (int tt = 0; tt < 4; ++tt) {
            if (tt < myTiles) {
                int mt = wave + tt * 8;
                int ob = mt * 16 + lg * 4;
                if (mt < 4) {
                    u16x4 r0, r1;
                    #pragma unroll
                    for (int i2 = 0; i2 < 4; ++i2) {
                        int o = ob + i2;
                        float cs = acc[tt][0][i2] + ((lr < 9) ? acc[tt][1][i2] : 0.f);
                        #pragma unroll
                        for (int mm = 1; mm < 16; mm <<= 1)
                            cs += __shfl_xor(cs, mm, 64);
                        float mu = (cs + b2s[i2]) * 0.04f;
                        ushort mur = f2b(mu);
                        float muf = b2f(mur);
                        r0[i2] = f2b(acc[tt][0][i2] + bias2[o * 25 + lr] - muf);
                        r1[i2] = (lr < 9)
                            ? f2b(acc[tt][1][i2] + bias2[o * 25 + 16 + lr] - muf)
                            : (ushort)0;
                        if (lr == 0) qmub[o] = mur;
                    }
                    *(u16x4*)(qkvT + qtswz(lr, ob)) = r0;
                    *(u16x4*)(qkvT + qtswz(16 + lr, ob)) = r1;
                } else if (mt < 12) {
                    u16x4 r0, r1;
                    #pragma unroll
                    for (int i2 = 0; i2 < 4; ++i2) {
                        int o = ob + i2;
                        r0[i2] = f2b(acc[tt][0][i2] + bias2[o * 25 + lr]);
                        r1[i2] = (lr < 9)
                            ? f2b(acc[tt][1][i2] + bias2[o * 25 + 16 + lr])
                            : (ushort)0;
                    }
                    *(u16x4*)(qkvT + qtswz(lr, ob)) = r0;
                    *(u16x4*)(qkvT + qtswz(16 + lr, ob)) = r1;
                } else {
                    #pragma unroll
                    for (int i2 = 0; i2 < 4; ++i2) {
                        int o = ob + i2;
                        int e = o - 192;
                        qkvV[qvswz(e, lr)] = f2b(acc[tt][0][i2] + bias2[o * 25 + lr]);
                        qkvV[qvswz(e, 16 + lr)] = (lr < 9)
                            ? f2b(acc[tt][1][i2] + bias2[o * 25 + 16 + lr])
                            : (ushort)0;
                    }
                }
            }
        }
    }
    __syncthreads();   // B2

    // ---- weights phase (wave = head h) ----
    int h = wave;
    bf16x8 mu8 = LD8(qmub + h * 8);
    bf16x8 aP1[2], aP2[2], bP1[2], bP2[2];
    #pragma unroll
    for (int mi = 0; mi < 2; ++mi) {
        int row = mi * 16 + lr, sx = row & 7;
        const ushort* rp = qkvT + row * 320;
        aP1[mi] = (lg == 0) ? LD8(rp + ((h ^ sx) << 3))
                : (lg == 1) ? LD8(rp + (((24 + h) ^ sx) << 3)) : zero8;
        aP2[mi] = (lg == 0) ? LD8(rp + (((24 + h) ^ sx) << 3))
                : (lg == 1) ? mu8 : zero8;
        bP1[mi] = (lg == 0) ? LD8(rp + (((8 + h) ^ sx) << 3))
                : (lg == 1) ? LD8(rp + (((32 + h) ^ sx) << 3)) : zero8;
        bP2[mi] = (lg == 0) ? LD8(rp + (((32 + h) ^ sx) << 3))
                : (lg == 1) ? LD8(rp + (((16 + h) ^ sx) << 3)) : zero8;
    }
    f32x4 p1[2][2], p2[2][2];
    #pragma unroll
    for (int mi = 0; mi < 2; ++mi)
        #pragma unroll
        for (int ni = 0; ni < 2; ++ni) {
            p1[mi][ni] = MFMA16(aP1[mi], bP1[ni], zacc);
            p2[mi][ni] = MFMA16(aP2[mi], bP2[ni], zacc);
        }
    __syncthreads();   // B3

    // ---- pbuf[h][v][w] = tanh(P1) + tanh(P2) ----
    #pragma unroll
    for (int mi = 0; mi < 2; ++mi)
        #pragma unroll
        for (int ni = 0; ni < 2; ++ni) {
            int w = ni * 16 + lr;
            #pragma unroll
            for (int i2 = 0; i2 < 4; ++i2) {
                int v = mi * 16 + lg * 4 + i2;
                float tw = tanh_fast(p1[mi][ni][i2]) + tanh_fast(p2[mi][ni][i2]);
                pbuf[(h * 32 + v) * 40 + w] = (w < 25) ? f2b(tw) : (ushort)0;
            }
        }

    // ---- attn: weights x V -> aT[v][e] ----
    {
        bf16x8 aw[2], bv[2];
        #pragma unroll
        for (int mi = 0; mi < 2; ++mi)
            aw[mi] = LD8(pbuf + (h * 32 + mi * 16 + lr) * 40 + lg * 8);
        #pragma unroll
        for (int ni = 0; ni < 2; ++ni) {
            int e = h * 32 + ni * 16 + lr;
            bv[ni] = LD8(qkvV + e * 32 + ((lg ^ (e & 3)) << 3));
        }
        f32x4 at_[2][2];
        #pragma unroll
        for (int mi = 0; mi < 2; ++mi)
            #pragma unroll
            for (int ni = 0; ni < 2; ++ni)
                at_[mi][ni] = MFMA16(aw[mi], bv[ni], zacc);
        #pragma unroll
        for (int mi = 0; mi < 2; ++mi)
            #pragma unroll
            for (int ni = 0; ni < 2; ++ni)
                #pragma unroll
                for (int i2 = 0; i2 < 4; ++i2) {
                    int v = mi * 16 + lg * 4 + i2;
                    int e = h * 32 + ni * 16 + lr;
                    if (v < 25) aT[bswz(v, e)] = f2b(at_[mi][ni][i2]);
                }
    }
    __syncthreads();   // B5

    // ---- GEMM2 + bf16 store + bn2 partials ----
    float sk0[2][4], sk1[2][4];
    #pragma unroll
    for (int tt = 0; tt < 2; ++tt)
        #pragma unroll
        for (int i2 = 0; i2 < 4; ++i2) {
            int o = (wave + tt * 8) * 16 + lg * 4 + i2;
            sk0[tt][i2] = xp[o * TV + lr];
            sk1[tt][i2] = (lr < 9) ? xp[o * TV + 16 + lr] : 0.f;
        }
    #pragma unroll
    for (int tt = 0; tt < 2; ++tt) {
        int o0 = (wave + tt * 8) * 16;
        const ushort* Arow = Wa + (o0 + lr) * 256;
        f32x4 a0 = zacc, a1 = zacc;
        #pragma unroll
        for (int kk = 0; kk < 8; ++kk) {
            int k0 = kk * 32 + lg * 8;
            int oct = (((k0 >> 3) ^ (lr & 7)) << 3);
            bf16x8 a  = LD8(Arow + k0);
            bf16x8 b0 = LD8(aT + lr * 256 + oct);
            bf16x8 b1 = LD8(aT + (16 + lr) * 256 + oct);
            a0 = MFMA16(a, b0, a0);
            a1 = MFMA16(a, b1, a1);
        }
        #pragma unroll
        for (int i2 = 0; i2 < 4; ++i2) {
            int o = o0 + lg * 4 + i2;
            float bias = attn_b[o];
            float v0 = a0[i2] + bias + sk0[tt][i2];
            yp[o * TV + lr] = f2b(v0);
            float v1 = 0.f;
            if (lr < 9) {
                v1 = a1[i2] + bias + sk1[tt][i2];
                yp[o * TV + 16 + lr] = f2b(v1);
            }
            float cs = v0 + v1, cq = v0 * v0 + v1 * v1;
            #pragma unroll
            for (int mm = 1; mm < 16; mm <<= 1) {
                cs += __shfl_xor(cs, mm, 64);
                cq += __shfl_xor(cq, mm, 64);
            }
            if (lr == 0) {
                atomicAdd(&mybins[o], cs);
                atomicAdd(&mybins[256 + o], cq);
            }
        }
    }
}

// ---------------- bn2 final + apply (bf16 in, f32 out) ----------------
__global__ void bn2_final_kernel(const float* __restrict__ bins,
                                 const float* __restrict__ gamma,
                                 const float* __restrict__ beta,
                                 float* __restrict__ scale,
                                 float* __restrict__ shift) {
    int c = threadIdx.x;
    float s = 0.f, q = 0.f;
    for (int cp = 0; cp < NCOPY; ++cp) {
        s += bins[cp * 512 + c];
        q += bins[cp * 512 + 256 + c];
    }
    float inv = 1.0f / (float)(N_ * TV);
    float mean = s * inv;
    float var = q * inv - mean * mean;
    float sc = rsqrtf(var + EPS_) * gamma[c];
    scale[c] = sc;
    shift[c] = beta[c] - mean * sc;
}

__global__ void bn2_apply_kernel(const ushort* __restrict__ ybf,
                                 float4* __restrict__ out,
                                 const float* __restrict__ scale,
                                 const float* __restrict__ shift) {
    const int total4 = N_ * CTV / 4;  // 6,553,600 groups of 4
    for (int i = blockIdx.x * blockDim.x + threadIdx.x; i < total4;
         i += gridDim.x * blockDim.x) {
        int c = (i / (TV / 4)) & 255;
        u16x4 yv = *(const u16x4*)(ybf + (size_t)i * 4);
        float sc = scale[c], sh = shift[c];
        float4 v;
        v.x = fmaxf(fmaf(b2f(yv[0]), sc, sh), 0.f);
        v.y = fmaxf(fmaf(b2f(yv[1]), sc, sh), 0.f);
        v.z = fmaxf(fmaf(b2f(yv[2]), sc, sh), 0.f);
        v.w = fmaxf(fmaf(b2f(yv[3]), sc, sh), 0.f);
        out[i] = v;
    }
}

extern "C" void kernel_launch(void* const* d_in, const int* in_sizes, int n_in,
                              void* d_out, int out_size, void* d_ws, size_t ws_size,
                              hipStream_t stream) {
    const float* x      = (const float*)d_in[0];
    const float* qkv_w  = (const float*)d_in[1];
    const float* qkv_b  = (const float*)d_in[2];
    const float* attn_w = (const float*)d_in[3];
    const float* attn_b = (const float*)d_in[4];
    const float* dbn_g  = (const float*)d_in[5];
    const float* dbn_b  = (const float*)d_in[6];
    const float* bn_g   = (const float*)d_in[7];
    const float* bn_b   = (const float*)d_in[8];
    float* out = (float*)d_out;

    char* ws = (char*)d_ws;
    ushort* Wq       = (ushort*)ws;                 // 229376 B
    ushort* Wa       = (ushort*)(ws + 229376);      // 131072 B
    float*  pe       = (float*)(ws + 360448);       // 25600 B
    float*  a_scale  = (float*)(ws + 386048);       // 25600 B
    float*  a_shift  = (float*)(ws + 411648);       // 25600 B
    float*  bias2    = (float*)(ws + 437248);       // 44800 B
    float*  peproj   = (float*)(ws + 482048);       // 12800 B
    float*  bias2sum = (float*)(ws + 494848);       // 256 B
    float*  bins     = (float*)(ws + 495104);       // 131072 B
    float*  bn2_sc   = (float*)(ws + 626176);       // 1024 B
    float*  bn2_sh   = (float*)(ws + 627200);       // 1024 B
    ushort* ybf      = (ushort*)(ws + 628224);      // 52,428,800 B (ws >= 186 MB verified r13)

    prep_kernel<<<256, 256, 0, stream>>>(qkv_w, attn_w, Wq, Wa, pe, bins);
    dbn_kernel<<<C_, 1024, 0, stream>>>(x, dbn_g, dbn_b, a_scale, a_shift);
    mkbias_kernel<<<57, 256, 0, stream>>>(Wq, qkv_b, a_shift, pe, bias2, peproj);
    b2sum_kernel<<<1, 64, 0, stream>>>(bias2, bias2sum);
    fused_kernel<<<N_ * T_, 512, 0, stream>>>(x, Wq, bias2, peproj, a_scale,
                                              bias2sum, Wa, attn_b, ybf, bins);
    bn2_final_kernel<<<1, 256, 0, stream>>>(bins, bn_g, bn_b, bn2_sc, bn2_sh);
    bn2_apply_kernel<<<4096, 256, 0, stream>>>(ybf, (float4*)out, bn2_sc, bn2_sh);
}

// Round 17
// 341.309 us; speedup vs baseline: 1.7557x; 1.0073x over previous
//
#include <hip/hip_runtime.h>
#include <hip/hip_bf16.h>
#include <math.h>

#define N_   32
#define C_   256
#define T_   128
#define V_   25
#define CTV  (C_ * T_ * V_)   // 819200
#define TV   (T_ * V_)        // 3200
#define EPS_ 1e-5f
#define S_Q  0.35355339059327373f
#define NCOPY 64

typedef __attribute__((ext_vector_type(8))) short bf16x8;
typedef __attribute__((ext_vector_type(4))) float f32x4;
typedef __attribute__((ext_vector_type(4))) unsigned short u16x4;

__device__ inline ushort f2b(float f) {
    __hip_bfloat16 h = __float2bfloat16(f);
    return *reinterpret_cast<ushort*>(&h);
}
__device__ inline float b2f(ushort u) {
    __hip_bfloat16 h;
    *reinterpret_cast<ushort*>(&h) = u;
    return __bfloat162float(h);
}
__device__ inline float tanh_fast(float x) {
    float xc = fminf(fmaxf(x, -12.f), 12.f);
    float e = __expf(xc + xc);
    return (e - 1.f) * __builtin_amdgcn_rcpf(e + 1.f);
}
#define LD8(p) (*(const bf16x8*)(p))
#define MFMA16(a, b, c) __builtin_amdgcn_mfma_f32_16x16x32_bf16(a, b, c, 0, 0, 0)

// qkvT (swizzled, [32 v][320]): cols 0..63 q(centered) | 64..127 k | 128..191 g | 192..255 pq | 256..319 pk
__device__ inline int qtswz(int v, int col) {
    return v * 320 + ((((col >> 3)) ^ (v & 7)) << 3) + (col & 7);
}
__device__ inline int qvswz(int e, int w) {     // qkvV [256][32]
    return e * 32 + (((w >> 3) ^ (e & 3)) << 3) + (w & 7);
}
__device__ inline int bswz(int v, int c) {      // B tiles / aT [32][256]
    return v * 256 + ((((c >> 3) ^ (v & 7)) << 3) | (c & 7));
}
__device__ inline int pbswz(int h, int v, int w) {  // pbuf [8][32][32] in region X
    return (h * 32 + v) * 32 + (((w >> 3) ^ (v & 3)) << 3) + (w & 7);
}

// ---------------- prep ----------------
__global__ void prep_kernel(const float* __restrict__ qkv_w,
                            const float* __restrict__ attn_w,
                            ushort* __restrict__ Wq, ushort* __restrict__ Wa,
                            float* __restrict__ pe, float* __restrict__ bins) {
    int idx = blockIdx.x * blockDim.x + threadIdx.x;
    int stride = gridDim.x * blockDim.x;
    for (int i = idx; i < 448 * 256; i += stride) {
        float w = qkv_w[i];
        if (i < 64 * 256) w *= S_Q;
        Wq[i] = f2b(w);
    }
    for (int i = idx; i < 256 * 256; i += stride) Wa[i] = f2b(attn_w[i]);
    for (int i = idx; i < C_ * V_; i += stride) {
        int c = i / V_, v = i - c * V_;
        int j2 = c & ~1;
        float ang = (float)v * expf(-logf(10000.0f) * (float)j2 / (float)C_);
        pe[i] = (c & 1) ? cosf(ang) : sinf(ang);
    }
    for (int i = idx; i < NCOPY * 512; i += stride) bins[i] = 0.f;
}

// ---------------- data_bn stats ----------------
__global__ __launch_bounds__(1024) void dbn_kernel(const float* __restrict__ x,
                                                   const float* __restrict__ gamma,
                                                   const float* __restrict__ beta,
                                                   float* __restrict__ a_scale,
                                                   float* __restrict__ a_shift) {
    __shared__ float pgS[32][25], pgQ[32][25];
    int c = blockIdx.x;
    int tid = threadIdx.x, g = tid >> 5, l = tid & 31;
    float s = 0.f, s2 = 0.f;
    if (l < 25) {
        const float* base = x + (size_t)g * CTV + c * TV + l;
        #pragma unroll 8
        for (int t = 0; t < 128; ++t) {
            float v = base[t * 25];
            s += v; s2 += v * v;
        }
        pgS[g][l] = s; pgQ[g][l] = s2;
    }
    __syncthreads();
    if (tid < 25) {
        float S = 0.f, Q = 0.f;
        #pragma unroll
        for (int g2 = 0; g2 < 32; ++g2) { S += pgS[g2][tid]; Q += pgQ[g2][tid]; }
        float inv = 1.0f / 4096.0f;
        float mean = S * inv, var = Q * inv - mean * mean;
        int f = c * 25 + tid;
        float sc = rsqrtf(var + EPS_) * gamma[f];
        a_scale[f] = sc;
        a_shift[f] = beta[f] - mean * sc;
    }
}

// ---------------- bias2 / peproj ----------------
__global__ void mkbias_kernel(const ushort* __restrict__ Wq,
                              const float* __restrict__ qkv_b,
                              const float* __restrict__ a_shift,
                              const float* __restrict__ pe,
                              float* __restrict__ bias2, float* __restrict__ peproj) {
    int id = blockIdx.x * 256 + threadIdx.x;
    if (id < 11200) {
        int o = id / 25, v = id - o * 25;
        float acc = qkv_b[o] * (o < 64 ? S_Q : 1.f);
        for (int c = 0; c < 256; ++c)
            acc = fmaf(b2f(Wq[o * 256 + c]), a_shift[c * 25 + v], acc);
        bias2[id] = acc;
    } else if (id < 14400) {
        int id2 = id - 11200;
        int r = id2 / 25, v = id2 - r * 25;
        float acc = qkv_b[r] * (r < 64 ? S_Q : 1.f);
        for (int c = 0; c < 256; ++c)
            acc = fmaf(b2f(Wq[r * 256 + c]), pe[c * 25 + v], acc);
        peproj[id2] = acc;
    }
}

__global__ void b2sum_kernel(const float* __restrict__ bias2,
                             float* __restrict__ bias2sum) {
    int o = threadIdx.x;   // 64
    float s = 0.f;
    #pragma unroll
    for (int v = 0; v < 25; ++v) s += bias2[o * 25 + v];
    bias2sum[o] = s;
}

// ---------------- fused per-token kernel (3-barrier version) ----------
// X [0,16384)      Braw -> pbuf [8][32][32] swz (wave-local)
// Y [16384,32768)  Bxn  -> aT
// Z [32768,53248)  qkvT
// W [53248,69632)  qkvV (dedicated)
// [69632,69760)    qmub
__global__ __launch_bounds__(512, 4) void fused_kernel(
        const float* __restrict__ x,
        const ushort* __restrict__ Wq,
        const float* __restrict__ bias2, const float* __restrict__ peproj,
        const float* __restrict__ a_scale, const float* __restrict__ bias2sum,
        const ushort* __restrict__ Wa, const float* __restrict__ attn_b,
        ushort* __restrict__ ybf, float* __restrict__ bins) {
    __shared__ __align__(16) char smem[69760];
    ushort* Braw = (ushort*)smem;
    ushort* pbuf = (ushort*)smem;
    ushort* Bxn  = (ushort*)(smem + 16384);
    ushort* aT   = (ushort*)(smem + 16384);
    ushort* qkvT = (ushort*)(smem + 32768);
    ushort* qkvV = (ushort*)(smem + 53248);
    ushort* qmub = (ushort*)(smem + 69632);

    int n = blockIdx.x >> 7, t = blockIdx.x & 127;
    int tid = threadIdx.x, wave = tid >> 6, lane = tid & 63;
    int lr = lane & 15, lg = lane >> 4;
    const float* xp = x + (size_t)n * CTV + t * V_;
    ushort* yp = ybf + (size_t)n * CTV + t * V_;
    float* mybins = bins + (blockIdx.x & (NCOPY - 1)) * 512;
    const f32x4 zacc = {0.f, 0.f, 0.f, 0.f};
    const bf16x8 zero8 = {0, 0, 0, 0, 0, 0, 0, 0};

    float b2s[4] = {0.f, 0.f, 0.f, 0.f};
    if (wave < 4) {
        #pragma unroll
        for (int i2 = 0; i2 < 4; ++i2)
            b2s[i2] = bias2sum[wave * 16 + lg * 4 + i2];
    }

    // ---- staging: register-ILP prefetch then LDS writes ----
    {
        float xv[13], sc[13];
        #pragma unroll
        for (int j = 0; j < 13; ++j) {
            int i = tid + j * 512;
            if (i < 6400) {
                int c = i / 25, v = i - c * 25;
                xv[j] = xp[c * TV + v];
                sc[j] = a_scale[i];
            }
        }
        #pragma unroll
        for (int j = 0; j < 13; ++j) {
            int i = tid + j * 512;
            if (i < 6400) {
                int c = i / 25, v = i - c * 25;
                int off = bswz(v, c);
                Braw[off] = f2b(xv[j]);
                Bxn[off]  = f2b(xv[j] * sc[j]);
            }
        }
        for (int i = tid; i < 448; i += 512) {
            int v = 25 + (i >> 6), cz = (i & 63) * 4;
            u16x4 z4 = {0, 0, 0, 0};
            *(u16x4*)(Braw + v * 256 + cz) = z4;
            *(u16x4*)(Bxn + v * 256 + cz) = z4;
        }
    }
    __syncthreads();   // B1

    // ---- pq/pk tile (1 per wave), reads Braw; epilogue -> qkvT (Z) ----
    {
        const ushort* Arow = Wq + (wave * 16 + lr) * 256;
        f32x4 a0 = zacc, a1 = zacc;
        #pragma unroll
        for (int kk = 0; kk < 8; ++kk) {
            int k0 = kk * 32 + lg * 8;
            int oct = (((k0 >> 3) ^ (lr & 7)) << 3);
            bf16x8 a  = LD8(Arow + k0);
            bf16x8 b0 = LD8(Braw + lr * 256 + oct);
            bf16x8 b1 = LD8(Braw + (16 + lr) * 256 + oct);
            a0 = MFMA16(a, b0, a0);
            a1 = MFMA16(a, b1, a1);
        }
        int rb = wave * 16 + lg * 4;
        u16x4 r0, r1;
        #pragma unroll
        for (int i2 = 0; i2 < 4; ++i2) {
            int r = rb + i2;
            r0[i2] = f2b(a0[i2] + peproj[r * 25 + lr]);
            r1[i2] = (lr < 9) ? f2b(a1[i2] + peproj[r * 25 + 16 + lr]) : (ushort)0;
        }
        *(u16x4*)(qkvT + qtswz(lr, 192 + rb)) = r0;
        *(u16x4*)(qkvT + qtswz(16 + lr, 192 + rb)) = r1;
    }

    // ---- q/k/g/v tiles (kk-outer, shared B frags); immediate epilogues ----
    {
        int myTiles = (wave < 4) ? 4 : 3;
        f32x4 acc[4][2];
        #pragma unroll
        for (int i = 0; i < 4; ++i) { acc[i][0] = zacc; acc[i][1] = zacc; }
        #pragma unroll
        for (int kk = 0; kk < 8; ++kk) {
            int k0 = kk * 32 + lg * 8;
            int oct = (((k0 >> 3) ^ (lr & 7)) << 3);
            bf16x8 b0 = LD8(Bxn + lr * 256 + oct);
            bf16x8 b1 = LD8(Bxn + (16 + lr) * 256 + oct);
            #pragma unroll
            for (int tt = 0; tt < 4; ++tt) {
                if (tt < myTiles) {
                    int mt = wave + tt * 8;
                    bf16x8 a = LD8(Wq + (mt * 16 + lr) * 256 + k0);
                    acc[tt][0] = MFMA16(a, b0, acc[tt][0]);
                    acc[tt][1] = MFMA16(a, b1, acc[tt][1]);
                }
            }
        }
        #pragma unroll
        for (int tt = 0; tt < 4; ++tt) {
            if (tt < myTiles) {
                int mt = wave + tt * 8;
                int ob = mt * 16 + lg * 4;
                if (mt < 4) {
                    u16x4 r0, r1;
                    #pragma unroll
                    for (int i2 = 0; i2 < 4; ++i2) {
                        int o = ob + i2;
                        float cs = acc[tt][0][i2] + ((lr < 9) ? acc[tt][1][i2] : 0.f);
                        #pragma unroll
                        for (int mm = 1; mm < 16; mm <<= 1)
                            cs += __shfl_xor(cs, mm, 64);
                        float mu = (cs + b2s[i2]) * 0.04f;
                        ushort mur = f2b(mu);
                        float muf = b2f(mur);
                        r0[i2] = f2b(acc[tt][0][i2] + bias2[o * 25 + lr] - muf);
                        r1[i2] = (lr < 9)
                            ? f2b(acc[tt][1][i2] + bias2[o * 25 + 16 + lr] - muf)
                            : (ushort)0;
                        if (lr == 0) qmub[o] = mur;
                    }
                    *(u16x4*)(qkvT + qtswz(lr, ob)) = r0;
                    *(u16x4*)(qkvT + qtswz(16 + lr, ob)) = r1;
                } else if (mt < 12) {
                    u16x4 r0, r1;
                    #pragma unroll
                    for (int i2 = 0; i2 < 4; ++i2) {
                        int o = ob + i2;
                        r0[i2] = f2b(acc[tt][0][i2] + bias2[o * 25 + lr]);
                        r1[i2] = (lr < 9)
                            ? f2b(acc[tt][1][i2] + bias2[o * 25 + 16 + lr])
                            : (ushort)0;
                    }
                    *(u16x4*)(qkvT + qtswz(lr, ob)) = r0;
                    *(u16x4*)(qkvT + qtswz(16 + lr, ob)) = r1;
                } else {
                    #pragma unroll
                    for (int i2 = 0; i2 < 4; ++i2) {
                        int o = ob + i2;
                        int e = o - 192;
                        qkvV[qvswz(e, lr)] = f2b(acc[tt][0][i2] + bias2[o * 25 + lr]);
                        qkvV[qvswz(e, 16 + lr)] = (lr < 9)
                            ? f2b(acc[tt][1][i2] + bias2[o * 25 + 16 + lr])
                            : (ushort)0;
                    }
                }
            }
        }
    }
    __syncthreads();   // B2: all Braw/Bxn reads + qkvT/qkvV/qmub writes done

    // ---- skip prefetch (latency hidden under weights+tanh+attn) ----
    float sk0[2][4], sk1[2][4];
    #pragma unroll
    for (int tt = 0; tt < 2; ++tt)
        #pragma unroll
        for (int i2 = 0; i2 < 4; ++i2) {
            int o = (wave + tt * 8) * 16 + lg * 4 + i2;
            sk0[tt][i2] = xp[o * TV + lr];
            sk1[tt][i2] = (lr < 9) ? xp[o * TV + 16 + lr] : 0.f;
        }

    // ---- weights phase (wave = head h) ----
    int h = wave;
    bf16x8 mu8 = LD8(qmub + h * 8);
    bf16x8 aP1[2], aP2[2], bP1[2], bP2[2];
    #pragma unroll
    for (int mi = 0; mi < 2; ++mi) {
        int row = mi * 16 + lr, sx = row & 7;
        const ushort* rp = qkvT + row * 320;
        aP1[mi] = (lg == 0) ? LD8(rp + ((h ^ sx) << 3))
                : (lg == 1) ? LD8(rp + (((24 + h) ^ sx) << 3)) : zero8;
        aP2[mi] = (lg == 0) ? LD8(rp + (((24 + h) ^ sx) << 3))
                : (lg == 1) ? mu8 : zero8;
        bP1[mi] = (lg == 0) ? LD8(rp + (((8 + h) ^ sx) << 3))
                : (lg == 1) ? LD8(rp + (((32 + h) ^ sx) << 3)) : zero8;
        bP2[mi] = (lg == 0) ? LD8(rp + (((32 + h) ^ sx) << 3))
                : (lg == 1) ? LD8(rp + (((16 + h) ^ sx) << 3)) : zero8;
    }
    f32x4 p1[2][2], p2[2][2];
    #pragma unroll
    for (int mi = 0; mi < 2; ++mi)
        #pragma unroll
        for (int ni = 0; ni < 2; ++ni) {
            p1[mi][ni] = MFMA16(aP1[mi], bP1[ni], zacc);
            p2[mi][ni] = MFMA16(aP2[mi], bP2[ni], zacc);
        }
    // (no barrier: pbuf lives in region X and is strictly wave-local)

    // ---- pbuf[h][v][w] = tanh(P1) + tanh(P2) ----
    #pragma unroll
    for (int mi = 0; mi < 2; ++mi)
        #pragma unroll
        for (int ni = 0; ni < 2; ++ni) {
            int w = ni * 16 + lr;
            #pragma unroll
            for (int i2 = 0; i2 < 4; ++i2) {
                int v = mi * 16 + lg * 4 + i2;
                float tw = tanh_fast(p1[mi][ni][i2]) + tanh_fast(p2[mi][ni][i2]);
                pbuf[pbswz(h, v, w)] = (w < 25) ? f2b(tw) : (ushort)0;
            }
        }

    // ---- attn: weights x V -> aT[v][e] ----
    {
        bf16x8 aw[2], bv[2];
        #pragma unroll
        for (int mi = 0; mi < 2; ++mi) {
            int v = mi * 16 + lr;
            aw[mi] = LD8(pbuf + (h * 32 + v) * 32 + ((lg ^ (v & 3)) << 3));
        }
        #pragma unroll
        for (int ni = 0; ni < 2; ++ni) {
            int e = h * 32 + ni * 16 + lr;
            bv[ni] = LD8(qkvV + e * 32 + ((lg ^ (e & 3)) << 3));
        }
        f32x4 at_[2][2];
        #pragma unroll
        for (int mi = 0; mi < 2; ++mi)
            #pragma unroll
            for (int ni = 0; ni < 2; ++ni)
                at_[mi][ni] = MFMA16(aw[mi], bv[ni], zacc);
        #pragma unroll
        for (int mi = 0; mi < 2; ++mi)
            #pragma unroll
            for (int ni = 0; ni < 2; ++ni)
                #pragma unroll
                for (int i2 = 0; i2 < 4; ++i2) {
                    int v = mi * 16 + lg * 4 + i2;
                    int e = h * 32 + ni * 16 + lr;
                    if (v < 25) aT[bswz(v, e)] = f2b(at_[mi][ni][i2]);
                }
    }
    __syncthreads();   // B5: aT complete (also covers pbuf-X vs nothing)

    // ---- GEMM2 + bf16 store + bn2 partials ----
    #pragma unroll
    for (int tt = 0; tt < 2; ++tt) {
        int o0 = (wave + tt * 8) * 16;
        const ushort* Arow = Wa + (o0 + lr) * 256;
        f32x4 a0 = zacc, a1 = zacc;
        #pragma unroll
        for (int kk = 0; kk < 8; ++kk) {
            int k0 = kk * 32 + lg * 8;
            int oct = (((k0 >> 3) ^ (lr & 7)) << 3);
            bf16x8 a  = LD8(Arow + k0);
            bf16x8 b0 = LD8(aT + lr * 256 + oct);
            bf16x8 b1 = LD8(aT + (16 + lr) * 256 + oct);
            a0 = MFMA16(a, b0, a0);
            a1 = MFMA16(a, b1, a1);
        }
        #pragma unroll
        for (int i2 = 0; i2 < 4; ++i2) {
            int o = o0 + lg * 4 + i2;
            float bias = attn_b[o];
            float v0 = a0[i2] + bias + sk0[tt][i2];
            yp[o * TV + lr] = f2b(v0);
            float v1 = 0.f;
            if (lr < 9) {
                v1 = a1[i2] + bias + sk1[tt][i2];
                yp[o * TV + 16 + lr] = f2b(v1);
            }
            float cs = v0 + v1, cq = v0 * v0 + v1 * v1;
            #pragma unroll
            for (int mm = 1; mm < 16; mm <<= 1) {
                cs += __shfl_xor(cs, mm, 64);
                cq += __shfl_xor(cq, mm, 64);
            }
            if (lr == 0) {
                atomicAdd(&mybins[o], cs);
                atomicAdd(&mybins[256 + o], cq);
            }
        }
    }
}

// ---------------- bn2 final + apply (bf16 in, f32 out) ----------------
__global__ void bn2_final_kernel(const float* __restrict__ bins,
                                 const float* __restrict__ gamma,
                                 const float* __restrict__ beta,
                                 float* __restrict__ scale,
                                 float* __restrict__ shift) {
    int c = threadIdx.x;
    float s = 0.f, q = 0.f;
    for (int cp = 0; cp < NCOPY; ++cp) {
        s += bins[cp * 512 + c];
        q += bins[cp * 512 + 256 + c];
    }
    float inv = 1.0f / (float)(N_ * TV);
    float mean = s * inv;
    float var = q * inv - mean * mean;
    float sc = rsqrtf(var + EPS_) * gamma[c];
    scale[c] = sc;
    shift[c] = beta[c] - mean * sc;
}

__global__ void bn2_apply_kernel(const ushort* __restrict__ ybf,
                                 float4* __restrict__ out,
                                 const float* __restrict__ scale,
                                 const float* __restrict__ shift) {
    const int total4 = N_ * CTV / 4;
    for (int i = blockIdx.x * blockDim.x + threadIdx.x; i < total4;
         i += gridDim.x * blockDim.x) {
        int c = (i / (TV / 4)) & 255;
        u16x4 yv = *(const u16x4*)(ybf + (size_t)i * 4);
        float sc = scale[c], sh = shift[c];
        float4 v;
        v.x = fmaxf(fmaf(b2f(yv[0]), sc, sh), 0.f);
        v.y = fmaxf(fmaf(b2f(yv[1]), sc, sh), 0.f);
        v.z = fmaxf(fmaf(b2f(yv[2]), sc, sh), 0.f);
        v.w = fmaxf(fmaf(b2f(yv[3]), sc, sh), 0.f);
        out[i] = v;
    }
}

extern "C" void kernel_launch(void* const* d_in, const int* in_sizes, int n_in,
                              void* d_out, int out_size, void* d_ws, size_t ws_size,
                              hipStream_t stream) {
    const float* x      = (const float*)d_in[0];
    const float* qkv_w  = (const float*)d_in[1];
    const float* qkv_b  = (const float*)d_in[2];
    const float* attn_w = (const float*)d_in[3];
    const float* attn_b = (const float*)d_in[4];
    const float* dbn_g  = (const float*)d_in[5];
    const float* dbn_b  = (const float*)d_in[6];
    const float* bn_g   = (const float*)d_in[7];
    const float* bn_b   = (const float*)d_in[8];
    float* out = (float*)d_out;

    char* ws = (char*)d_ws;
    ushort* Wq       = (ushort*)ws;                 // 229376 B
    ushort* Wa       = (ushort*)(ws + 229376);      // 131072 B
    float*  pe       = (float*)(ws + 360448);       // 25600 B
    float*  a_scale  = (float*)(ws + 386048);       // 25600 B
    float*  a_shift  = (float*)(ws + 411648);       // 25600 B
    float*  bias2    = (float*)(ws + 437248);       // 44800 B
    float*  peproj   = (float*)(ws + 482048);       // 12800 B
    float*  bias2sum = (float*)(ws + 494848);       // 256 B
    float*  bins     = (float*)(ws + 495104);       // 131072 B
    float*  bn2_sc   = (float*)(ws + 626176);       // 1024 B
    float*  bn2_sh   = (float*)(ws + 627200);       // 1024 B
    ushort* ybf      = (ushort*)(ws + 628224);      // 52,428,800 B (ws >= 186 MB verified r13)

    prep_kernel<<<256, 256, 0, stream>>>(qkv_w, attn_w, Wq, Wa, pe, bins);
    dbn_kernel<<<C_, 1024, 0, stream>>>(x, dbn_g, dbn_b, a_scale, a_shift);
    mkbias_kernel<<<57, 256, 0, stream>>>(Wq, qkv_b, a_shift, pe, bias2, peproj);
    b2sum_kernel<<<1, 64, 0, stream>>>(bias2, bias2sum);
    fused_kernel<<<N_ * T_, 512, 0, stream>>>(x, Wq, bias2, peproj, a_scale,
                                              bias2sum, Wa, attn_b, ybf, bins);
    bn2_final_kernel<<<1, 256, 0, stream>>>(bins, bn_g, bn_b, bn2_sc, bn2_sh);
    bn2_apply_kernel<<<4096, 256, 0, stream>>>(ybf, (float4*)out, bn2_sc, bn2_sh);
}